// Round 1
// baseline (17333.893 us; speedup 1.0000x reference)
//
#include <hip/hip_runtime.h>
#include <cstddef>

#define T_  128
#define B_  64
#define F_  75
#define H_  512
#define G4_ 2048
#define TB_ (T_ * B_)

// ---------------------------------------------------------------------------
// Generic tiled fp32 GEMM: C(M,N) = act( A(M,K) @ B(N,K)^T + bias1 + bias2 )
// act: 0 = none, 1 = tanh, 2 = exp
// ---------------------------------------------------------------------------
__global__ __launch_bounds__(256) void gemm_bt(
    const float* __restrict__ A, const float* __restrict__ Bm,
    float* __restrict__ C, int M, int N, int K,
    const float* __restrict__ bias1, const float* __restrict__ bias2, int act)
{
    __shared__ float As[16][68];
    __shared__ float Bs[16][68];
    const int tid = threadIdx.x;
    const int m_base = blockIdx.y * 64;
    const int n_base = blockIdx.x * 64;
    const int tm = tid >> 4, tn = tid & 15;
    float acc[4][4] = {};

    for (int k0 = 0; k0 < K; k0 += 16) {
#pragma unroll
        for (int i = 0; i < 4; i++) {
            int idx = tid * 4 + i;
            int r = idx >> 4, kk = idx & 15;
            int gm = m_base + r, gk = k0 + kk;
            As[kk][r] = (gm < M && gk < K) ? A[(size_t)gm * K + gk] : 0.f;
            int gn = n_base + r;
            Bs[kk][r] = (gn < N && gk < K) ? Bm[(size_t)gn * K + gk] : 0.f;
        }
        __syncthreads();
#pragma unroll
        for (int kk = 0; kk < 16; kk++) {
            float4 av = *(const float4*)&As[kk][tm * 4];
            float4 bv = *(const float4*)&Bs[kk][tn * 4];
            float a[4] = {av.x, av.y, av.z, av.w};
            float b[4] = {bv.x, bv.y, bv.z, bv.w};
#pragma unroll
            for (int i = 0; i < 4; i++)
#pragma unroll
                for (int j = 0; j < 4; j++)
                    acc[i][j] = fmaf(a[i], b[j], acc[i][j]);
        }
        __syncthreads();
    }

#pragma unroll
    for (int i = 0; i < 4; i++) {
        int gm = m_base + tm * 4 + i;
        if (gm >= M) continue;
#pragma unroll
        for (int j = 0; j < 4; j++) {
            int gn = n_base + tn * 4 + j;
            if (gn >= N) continue;
            float v = acc[i][j];
            if (bias1) v += bias1[gn];
            if (bias2) v += bias2[gn];
            if (act == 1) v = tanhf(v);
            else if (act == 2) v = expf(v);
            C[(size_t)gm * N + gn] = v;
        }
    }
}

// ---------------------------------------------------------------------------
// One LSTM time step, both directions. grid = (64 unit-blocks, 2 dirs).
// Each block: 8 hidden units -> 32 gate columns x 64 batch, K = 512.
// gates = XW[dir][t] + h @ Whh[dir]^T ; then pointwise c,h update.
// Double-buffered h (Hin read-only, Hout written). C state private per unit.
// ---------------------------------------------------------------------------
__global__ __launch_bounds__(256) void lstm_step(
    const float* __restrict__ XW,   // (2,T,B,4H) input proj (+biases)
    const float* __restrict__ Whh,  // (2,4H,H)
    const float* __restrict__ Hin,  // (2,B,H)
    float* __restrict__ Hout,       // (2,B,H)
    float* __restrict__ Cst,        // (2,B,H)
    float* __restrict__ Y,          // (T,B,2H) or nullptr
    int s)
{
    const int dir = blockIdx.y;
    const int ub = blockIdx.x;          // 0..63
    const int u_base = ub * 8;
    const int t = dir ? (T_ - 1 - s) : s;
    __shared__ float Hs[16][68];
    __shared__ float Ws[16][36];
    __shared__ float gbuf[64][33];
    const float* Wd = Whh + (size_t)dir * G4_ * H_;
    const float* Hd = Hin + (size_t)dir * B_ * H_;
    const int tid = threadIdx.x;
    const int tm = tid >> 4, tn = tid & 15;
    float acc[4][2] = {};

    for (int k0 = 0; k0 < H_; k0 += 16) {
#pragma unroll
        for (int i = 0; i < 4; i++) {
            int idx = tid * 4 + i;
            int r = idx >> 4, kk = idx & 15;
            Hs[kk][r] = Hd[(size_t)r * H_ + k0 + kk];
        }
#pragma unroll
        for (int i = 0; i < 2; i++) {
            int idx = tid * 2 + i;
            int r = idx >> 4, kk = idx & 15;   // r: 0..31
            int g = r >> 3, j = r & 7;
            Ws[kk][r] = Wd[(size_t)(g * H_ + u_base + j) * H_ + k0 + kk];
        }
        __syncthreads();
#pragma unroll
        for (int kk = 0; kk < 16; kk++) {
            float4 av = *(const float4*)&Hs[kk][tm * 4];
            float2 bv = *(const float2*)&Ws[kk][tn * 2];
            acc[0][0] = fmaf(av.x, bv.x, acc[0][0]);
            acc[0][1] = fmaf(av.x, bv.y, acc[0][1]);
            acc[1][0] = fmaf(av.y, bv.x, acc[1][0]);
            acc[1][1] = fmaf(av.y, bv.y, acc[1][1]);
            acc[2][0] = fmaf(av.z, bv.x, acc[2][0]);
            acc[2][1] = fmaf(av.z, bv.y, acc[2][1]);
            acc[3][0] = fmaf(av.w, bv.x, acc[3][0]);
            acc[3][1] = fmaf(av.w, bv.y, acc[3][1]);
        }
        __syncthreads();
    }

#pragma unroll
    for (int i = 0; i < 4; i++)
#pragma unroll
        for (int j = 0; j < 2; j++)
            gbuf[tm * 4 + i][tn * 2 + j] = acc[i][j];
    __syncthreads();

    const float* XWd = XW + ((size_t)dir * T_ + t) * B_ * G4_;
#pragma unroll
    for (int q = 0; q < 2; q++) {
        int p = tid * 2 + q;        // 0..511
        int b = p >> 3, j = p & 7;
        int u = u_base + j;
        float gi = gbuf[b][j]      + XWd[(size_t)b * G4_ + 0 * H_ + u];
        float gf = gbuf[b][8 + j]  + XWd[(size_t)b * G4_ + 1 * H_ + u];
        float gg = gbuf[b][16 + j] + XWd[(size_t)b * G4_ + 2 * H_ + u];
        float go = gbuf[b][24 + j] + XWd[(size_t)b * G4_ + 3 * H_ + u];
        float ii = 1.f / (1.f + expf(-gi));
        float ff = 1.f / (1.f + expf(-gf));
        float oo = 1.f / (1.f + expf(-go));
        float tg = tanhf(gg);
        size_t ci = (size_t)dir * B_ * H_ + (size_t)b * H_ + u;
        float c = ff * Cst[ci] + ii * tg;
        Cst[ci] = c;
        float h = oo * tanhf(c);
        Hout[ci] = h;
        if (Y) Y[((size_t)t * B_ + b) * (2 * H_) + dir * H_ + u] = h;
    }
}

// ---------------------------------------------------------------------------
__global__ __launch_bounds__(256) void init_hc(
    const float* __restrict__ h0s, const float* __restrict__ c0s,
    float* __restrict__ Hb, float* __restrict__ Cb)
{
    int i = blockIdx.x * 256 + threadIdx.x;
    if (i < 2 * B_ * H_) {
        Hb[i] = h0s[i];
        Cb[i] = c0s[i];
    }
}

// Attention normalization: per batch b over (dir, J) = 150 values.
__global__ __launch_bounds__(256) void attn_alpha(
    const float* __restrict__ E, float* __restrict__ AB)
{
    const int b = blockIdx.x, tid = threadIdx.x;
    __shared__ float red[256];
    __shared__ float adj[152];
    float v = 0.f;
    if (tid < 150) {
        int d = tid / F_, j = tid % F_;
        v = E[((size_t)d * B_ + b) * F_ + j];
    }
    red[tid] = v; __syncthreads();
    for (int s2 = 128; s2 > 0; s2 >>= 1) {
        if (tid < s2) red[tid] += red[tid + s2];
        __syncthreads();
    }
    float total = red[0]; __syncthreads();
    float alpha = v / total;
    float m = (tid < 150 && alpha >= 0.1f) ? 1.f : 0.f;
    red[tid] = m; __syncthreads();
    for (int s2 = 128; s2 > 0; s2 >>= 1) {
        if (tid < s2) red[tid] += red[tid + s2];
        __syncthreads();
    }
    float cnt = red[0]; __syncthreads();
    red[tid] = m * alpha; __syncthreads();
    for (int s2 = 128; s2 > 0; s2 >>= 1) {
        if (tid < s2) red[tid] += red[tid + s2];
        __syncthreads();
    }
    float selsum = red[0]; __syncthreads();
    float selmean = selsum / fmaxf(cnt, 1.f);
    if (tid < 150) adj[tid] = (m > 0.f) ? selmean : alpha;
    __syncthreads();
    if (tid < F_) AB[(size_t)b * F_ + tid] = 0.5f * (adj[tid] + adj[F_ + tid]);
}

__global__ __launch_bounds__(256) void scale_x(
    const float* __restrict__ x, const float* __restrict__ AB,
    float* __restrict__ XWX)
{
    int i = blockIdx.x * 256 + threadIdx.x;
    if (i < TB_ * F_) {
        int f = i % F_;
        int b = (i / F_) % B_;
        XWX[i] = x[i] * AB[b * F_ + f];
    }
}

// ---------------------------------------------------------------------------
extern "C" void kernel_launch(void* const* d_in, const int* in_sizes, int n_in,
                              void* d_out, int out_size, void* d_ws, size_t ws_size,
                              hipStream_t stream)
{
    (void)in_sizes; (void)n_in; (void)out_size; (void)ws_size;
    const float* x       = (const float*)d_in[0];
    const float* h0      = (const float*)d_in[1];
    const float* c0      = (const float*)d_in[2];
    const float* sa_Wih  = (const float*)d_in[3];
    const float* sa_Whh  = (const float*)d_in[4];
    const float* sa_bih  = (const float*)d_in[5];
    const float* sa_bhh  = (const float*)d_in[6];
    const float* m0_Wih  = (const float*)d_in[7];
    const float* m0_Whh  = (const float*)d_in[8];
    const float* m0_bih  = (const float*)d_in[9];
    const float* m0_bhh  = (const float*)d_in[10];
    const float* mL_Wih  = (const float*)d_in[11];
    const float* mL_Whh  = (const float*)d_in[12];
    const float* mL_bih  = (const float*)d_in[13];
    const float* mL_bhh  = (const float*)d_in[14];
    const float* safc1_W = (const float*)d_in[15];
    const float* safc1_b = (const float*)d_in[16];
    const float* safc2_W = (const float*)d_in[17];
    const float* safc2_b = (const float*)d_in[18];
    const float* fc1_W   = (const float*)d_in[19];
    const float* fc1_b   = (const float*)d_in[20];

    float* ws = (float*)d_ws;
    size_t off = 0;
    float* XW  = ws + off; off += (size_t)2 * TB_ * G4_;   // 33.55M
    float* Y0  = ws + off; off += (size_t)TB_ * 2 * H_;    // 8.39M
    float* Y1  = ws + off; off += (size_t)TB_ * 2 * H_;    // 8.39M
    float* HB0 = ws + off; off += 2 * B_ * H_;
    float* HB1 = ws + off; off += 2 * B_ * H_;
    float* CB  = ws + off; off += 2 * B_ * H_;
    float* T1b = ws + off; off += 2 * B_ * H_;
    float* Eb  = ws + off; off += 2 * B_ * F_;
    float* AB  = ws + off; off += B_ * F_;
    float* XWX = ws + off; off += (size_t)TB_ * F_;

    auto gemm = [&](const float* Ap, const float* Bp, float* Cp, int M, int N, int K,
                    const float* b1, const float* b2, int act) {
        dim3 g((N + 63) / 64, (M + 63) / 64);
        gemm_bt<<<g, 256, 0, stream>>>(Ap, Bp, Cp, M, N, K, b1, b2, act);
    };
    auto run_phase = [&](const float* Whh_base, float* Yout) {
        for (int s = 0; s < T_; s++) {
            float* Hin  = (s & 1) ? HB1 : HB0;
            float* Hout = (s & 1) ? HB0 : HB1;
            lstm_step<<<dim3(64, 2), 256, 0, stream>>>(XW, Whh_base, Hin, Hout, CB, Yout, s);
        }
    };

    // ---- Phase A: spatial-attention BiLSTM (only final hidden needed) ----
    init_hc<<<256, 256, 0, stream>>>(h0, c0, HB0, CB);
    for (int d = 0; d < 2; d++)
        gemm(x, sa_Wih + (size_t)d * G4_ * F_, XW + (size_t)d * TB_ * G4_,
             TB_, G4_, F_, sa_bih + d * G4_, sa_bhh + d * G4_, 0);
    run_phase(sa_Whh, nullptr);
    // final h lives in HB0 (T even). Attention:
    gemm(HB0, safc1_W, T1b, 2 * B_, H_, H_, safc1_b, nullptr, 1);   // tanh
    gemm(T1b, safc2_W, Eb, 2 * B_, F_, H_, safc2_b, nullptr, 2);    // exp
    attn_alpha<<<B_, 256, 0, stream>>>(Eb, AB);
    scale_x<<<(TB_ * F_ + 255) / 256, 256, 0, stream>>>(x, AB, XWX);

    // ---- Phase B: main layer 0 (input F) ----
    init_hc<<<256, 256, 0, stream>>>(h0, c0, HB0, CB);
    for (int d = 0; d < 2; d++)
        gemm(XWX, m0_Wih + (size_t)d * G4_ * F_, XW + (size_t)d * TB_ * G4_,
             TB_, G4_, F_, m0_bih + d * G4_, m0_bhh + d * G4_, 0);
    run_phase(m0_Whh, Y0);

    // ---- Phase C: main layer 1 (input 2H) ----
    init_hc<<<256, 256, 0, stream>>>(h0 + 2 * B_ * H_, c0 + 2 * B_ * H_, HB0, CB);
    for (int d = 0; d < 2; d++)
        gemm(Y0, mL_Wih + (size_t)(0 * 2 + d) * G4_ * 2 * H_, XW + (size_t)d * TB_ * G4_,
             TB_, G4_, 2 * H_, mL_bih + (0 * 2 + d) * G4_, mL_bhh + (0 * 2 + d) * G4_, 0);
    run_phase(mL_Whh + (size_t)0 * 2 * G4_ * H_, Y1);

    // ---- Phase D: main layer 2 (input 2H) ----
    init_hc<<<256, 256, 0, stream>>>(h0 + 4 * B_ * H_, c0 + 4 * B_ * H_, HB0, CB);
    for (int d = 0; d < 2; d++)
        gemm(Y1, mL_Wih + (size_t)(1 * 2 + d) * G4_ * 2 * H_, XW + (size_t)d * TB_ * G4_,
             TB_, G4_, 2 * H_, mL_bih + (1 * 2 + d) * G4_, mL_bhh + (1 * 2 + d) * G4_, 0);
    run_phase(mL_Whh + (size_t)1 * 2 * G4_ * H_, Y0);

    // ---- FC1 ----
    gemm(Y0, fc1_W, (float*)d_out, TB_, H_, 2 * H_, fc1_b, nullptr, 0);
}

// Round 2
// 8079.082 us; speedup vs baseline: 2.1455x; 2.1455x over previous
//
#include <hip/hip_runtime.h>
#include <cstddef>

#define T_  128
#define B_  64
#define F_  75
#define H_  512
#define G4_ 2048
#define TB_ (T_ * B_)
#define KP_ 128   // padded K for F=75 inputs

typedef __bf16 bf16x8 __attribute__((ext_vector_type(8)));
typedef float  f32x4  __attribute__((ext_vector_type(4)));

__device__ __forceinline__ short f2b(float x) {
    union { float f; unsigned u; } v; v.f = x;
    return (short)((v.u + 0x7fffu + ((v.u >> 16) & 1u)) >> 16);
}
__device__ __forceinline__ float b2f(short s) {
    union { float f; unsigned u; } v; v.u = ((unsigned)(unsigned short)s) << 16;
    return v.f;
}
__device__ __forceinline__ void gload16(const void* g, void* l) {
    __builtin_amdgcn_global_load_lds(
        (const __attribute__((address_space(1))) void*)g,
        (__attribute__((address_space(3))) void*)l, 16, 0, 0);
}

// ---------------------------------------------------------------------------
// bf16 MFMA GEMM: C(M,N) fp32 = A_bf16(M,K) @ B_bf16(N,K)^T + bias1 + bias2
// M,N multiples of 128; K multiple of 32. 256 thr = 4 waves, 128x128 tile.
// ---------------------------------------------------------------------------
__global__ __launch_bounds__(256) void gemm_bf16(
    const short* __restrict__ A, const short* __restrict__ Bm,
    float* __restrict__ C, int M, int N, int K,
    const float* __restrict__ bias1, const float* __restrict__ bias2)
{
    __shared__ short As[4096];   // [kc 4][row 128][8] bf16 = 8KB
    __shared__ short Bs[4096];
    const int tid = threadIdx.x;
    const int m_base = blockIdx.y * 128;
    const int n_base = blockIdx.x * 128;
    const int w = tid >> 6, lane = tid & 63;
    const int wm = (w >> 1) * 64, wn = (w & 1) * 64;
    const int lm = lane & 15, q = lane >> 4;

    f32x4 acc[4][4];
#pragma unroll
    for (int i = 0; i < 4; i++)
#pragma unroll
        for (int j = 0; j < 4; j++)
#pragma unroll
            for (int r = 0; r < 4; r++) acc[i][j][r] = 0.f;

    const int s0 = tid, s1 = tid + 256;
    const int r0 = s0 & 127, c0 = s0 >> 7;
    const int r1 = s1 & 127, c1 = s1 >> 7;

    for (int k0 = 0; k0 < K; k0 += 32) {
        __syncthreads();
        gload16(A + (size_t)(m_base + r0) * K + k0 + c0 * 8, &As[s0 * 8]);
        gload16(A + (size_t)(m_base + r1) * K + k0 + c1 * 8, &As[s1 * 8]);
        gload16(Bm + (size_t)(n_base + r0) * K + k0 + c0 * 8, &Bs[s0 * 8]);
        gload16(Bm + (size_t)(n_base + r1) * K + k0 + c1 * 8, &Bs[s1 * 8]);
        __syncthreads();
        bf16x8 af[4], bfv[4];
#pragma unroll
        for (int i = 0; i < 4; i++) {
            af[i]  = *(const bf16x8*)&As[((q * 128) + wm + i * 16 + lm) * 8];
            bfv[i] = *(const bf16x8*)&Bs[((q * 128) + wn + i * 16 + lm) * 8];
        }
#pragma unroll
        for (int i = 0; i < 4; i++)
#pragma unroll
            for (int j = 0; j < 4; j++)
                acc[i][j] = __builtin_amdgcn_mfma_f32_16x16x32_bf16(
                    af[i], bfv[j], acc[i][j], 0, 0, 0);
    }

#pragma unroll
    for (int i = 0; i < 4; i++) {
#pragma unroll
        for (int j = 0; j < 4; j++) {
            const int gm = m_base + wm + i * 16 + q * 4;
            const int gn = n_base + wn + j * 16 + lm;
            float bb = (bias1 ? bias1[gn] : 0.f) + (bias2 ? bias2[gn] : 0.f);
#pragma unroll
            for (int r = 0; r < 4; r++)
                C[(size_t)(gm + r) * N + gn] = acc[i][j][r] + bb;
        }
    }
}

// ---------------------------------------------------------------------------
// MFMA LSTM step, both dirs. grid (32, 2): block = 16 units x 4 gates x 64 b.
// h bf16 (staged to LDS once), Whh bf16 from L2, c fp32, gates fused in-reg.
// ---------------------------------------------------------------------------
__global__ __launch_bounds__(256) void lstm_step_mfma(
    const float* __restrict__ XW,    // (2,T,B,4H) fp32, includes biases
    const short* __restrict__ Whb,   // (2,4H,H) bf16
    const short* __restrict__ Hprev, // (2,B,H) bf16
    short* __restrict__ Hnext,       // (2,B,H) bf16
    float* __restrict__ Cst,         // (2,B,H) fp32
    short* __restrict__ Y,           // (T,B,2H) bf16 or null
    int s)
{
    __shared__ short Hs[32768];      // [kc 64][row 64][8] = 64KB
    const int dir = blockIdx.y;
    const int u0 = blockIdx.x * 16;
    const int t = dir ? (T_ - 1 - s) : s;
    const int tid = threadIdx.x;
    const int w = tid >> 6, lane = tid & 63;
    const int lm = lane & 15, q = lane >> 4;

    const short* Hd = Hprev + dir * B_ * H_;
#pragma unroll
    for (int p = 0; p < 16; p++) {
        int sg = tid + 256 * p;
        int r = sg & 63, kc = sg >> 6;
        gload16(Hd + r * H_ + kc * 8, &Hs[sg * 8]);
    }

    const short* Wd = Whb + (size_t)dir * G4_ * H_;
    f32x4 acc[4];
#pragma unroll
    for (int g = 0; g < 4; g++)
#pragma unroll
        for (int r = 0; r < 4; r++) acc[g][r] = 0.f;

    __syncthreads();   // drains global_load_lds (vmcnt) + barrier

#pragma unroll 4
    for (int it = 0; it < 16; it++) {
        bf16x8 af = *(const bf16x8*)&Hs[((it * 4 + q) * 64 + w * 16 + lm) * 8];
#pragma unroll
        for (int g = 0; g < 4; g++) {
            const bf16x8 bv = *(const bf16x8*)(
                Wd + (size_t)(g * H_ + u0 + lm) * H_ + it * 32 + q * 8);
            acc[g] = __builtin_amdgcn_mfma_f32_16x16x32_bf16(af, bv, acc[g], 0, 0, 0);
        }
    }

    const float* XWd = XWd = XW + ((size_t)dir * T_ + t) * B_ * G4_;
    const int u = u0 + lm;
#pragma unroll
    for (int r = 0; r < 4; r++) {
        const int b = w * 16 + q * 4 + r;
        const float* xwrow = XWd + (size_t)b * G4_;
        float gi = acc[0][r] + xwrow[u];
        float gf = acc[1][r] + xwrow[H_ + u];
        float gg = acc[2][r] + xwrow[2 * H_ + u];
        float go = acc[3][r] + xwrow[3 * H_ + u];
        float ii = 1.f / (1.f + expf(-gi));
        float ff = 1.f / (1.f + expf(-gf));
        float oo = 1.f / (1.f + expf(-go));
        float tg = tanhf(gg);
        size_t ci = (size_t)dir * B_ * H_ + (size_t)b * H_ + u;
        float c = ff * Cst[ci] + ii * tg;
        Cst[ci] = c;
        float h = oo * tanhf(c);
        Hnext[ci] = f2b(h);
        if (Y) Y[((size_t)t * B_ + b) * (2 * H_) + dir * H_ + u] = f2b(h);
    }
}

// ---------------------------------------------------------------------------
// fp32 GEMM for the tiny attention matmuls (bounds-checked), act 0/1/2
// ---------------------------------------------------------------------------
__global__ __launch_bounds__(256) void gemm_bt(
    const float* __restrict__ A, const float* __restrict__ Bm,
    float* __restrict__ C, int M, int N, int K,
    const float* __restrict__ bias1, int act)
{
    __shared__ float As[16][68];
    __shared__ float Bs[16][68];
    const int tid = threadIdx.x;
    const int m_base = blockIdx.y * 64;
    const int n_base = blockIdx.x * 64;
    const int tm = tid >> 4, tn = tid & 15;
    float acc[4][4] = {};

    for (int k0 = 0; k0 < K; k0 += 16) {
#pragma unroll
        for (int i = 0; i < 4; i++) {
            int idx = tid * 4 + i;
            int r = idx >> 4, kk = idx & 15;
            int gm = m_base + r, gk = k0 + kk;
            As[kk][r] = (gm < M && gk < K) ? A[(size_t)gm * K + gk] : 0.f;
            int gn = n_base + r;
            Bs[kk][r] = (gn < N && gk < K) ? Bm[(size_t)gn * K + gk] : 0.f;
        }
        __syncthreads();
#pragma unroll
        for (int kk = 0; kk < 16; kk++) {
            float4 av = *(const float4*)&As[kk][tm * 4];
            float4 bv = *(const float4*)&Bs[kk][tn * 4];
            float a[4] = {av.x, av.y, av.z, av.w};
            float b[4] = {bv.x, bv.y, bv.z, bv.w};
#pragma unroll
            for (int i = 0; i < 4; i++)
#pragma unroll
                for (int j = 0; j < 4; j++)
                    acc[i][j] = fmaf(a[i], b[j], acc[i][j]);
        }
        __syncthreads();
    }
#pragma unroll
    for (int i = 0; i < 4; i++) {
        int gm = m_base + tm * 4 + i;
        if (gm >= M) continue;
#pragma unroll
        for (int j = 0; j < 4; j++) {
            int gn = n_base + tn * 4 + j;
            if (gn >= N) continue;
            float v = acc[i][j];
            if (bias1) v += bias1[gn];
            if (act == 1) v = tanhf(v);
            else if (act == 2) v = expf(v);
            C[(size_t)gm * N + gn] = v;
        }
    }
}

// ---------------------------------------------------------------------------
__global__ __launch_bounds__(256) void conv_f2b(
    const float* __restrict__ src, short* __restrict__ dst, int n)
{
    int i = blockIdx.x * 256 + threadIdx.x;
    if (i < n) dst[i] = f2b(src[i]);
}
__global__ __launch_bounds__(256) void conv_f2b_pad(
    const float* __restrict__ src, short* __restrict__ dst,
    int rows, int kin, int kp)
{
    int i = blockIdx.x * 256 + threadIdx.x;
    if (i < rows * kp) {
        int r = i / kp, k = i % kp;
        dst[i] = (k < kin) ? f2b(src[(size_t)r * kin + k]) : (short)0;
    }
}
__global__ __launch_bounds__(256) void conv_b2f(
    const short* __restrict__ src, float* __restrict__ dst, int n)
{
    int i = blockIdx.x * 256 + threadIdx.x;
    if (i < n) dst[i] = b2f(src[i]);
}
__global__ __launch_bounds__(256) void init_hc2(
    const float* __restrict__ h0s, const float* __restrict__ c0s,
    short* __restrict__ Hb, float* __restrict__ Cb)
{
    int i = blockIdx.x * 256 + threadIdx.x;
    if (i < 2 * B_ * H_) {
        Hb[i] = f2b(h0s[i]);
        Cb[i] = c0s[i];
    }
}

__global__ __launch_bounds__(256) void attn_alpha(
    const float* __restrict__ E, float* __restrict__ AB)
{
    const int b = blockIdx.x, tid = threadIdx.x;
    __shared__ float red[256];
    __shared__ float adj[152];
    float v = 0.f;
    if (tid < 150) {
        int d = tid / F_, j = tid % F_;
        v = E[((size_t)d * B_ + b) * F_ + j];
    }
    red[tid] = v; __syncthreads();
    for (int s2 = 128; s2 > 0; s2 >>= 1) {
        if (tid < s2) red[tid] += red[tid + s2];
        __syncthreads();
    }
    float total = red[0]; __syncthreads();
    float alpha = v / total;
    float m = (tid < 150 && alpha >= 0.1f) ? 1.f : 0.f;
    red[tid] = m; __syncthreads();
    for (int s2 = 128; s2 > 0; s2 >>= 1) {
        if (tid < s2) red[tid] += red[tid + s2];
        __syncthreads();
    }
    float cnt = red[0]; __syncthreads();
    red[tid] = m * alpha; __syncthreads();
    for (int s2 = 128; s2 > 0; s2 >>= 1) {
        if (tid < s2) red[tid] += red[tid + s2];
        __syncthreads();
    }
    float selsum = red[0]; __syncthreads();
    float selmean = selsum / fmaxf(cnt, 1.f);
    if (tid < 150) adj[tid] = (m > 0.f) ? selmean : alpha;
    __syncthreads();
    if (tid < F_) AB[(size_t)b * F_ + tid] = 0.5f * (adj[tid] + adj[F_ + tid]);
}

// x*alpha -> bf16, padded to KP_
__global__ __launch_bounds__(256) void scale_xb(
    const float* __restrict__ x, const float* __restrict__ AB,
    short* __restrict__ xb)
{
    int i = blockIdx.x * 256 + threadIdx.x;
    if (i < TB_ * KP_) {
        int r = i >> 7, k = i & 127;
        if (k < F_) {
            int b = r % B_;
            xb[i] = f2b(x[(size_t)r * F_ + k] * AB[(size_t)b * F_ + k]);
        } else xb[i] = 0;
    }
}

// ---------------------------------------------------------------------------
extern "C" void kernel_launch(void* const* d_in, const int* in_sizes, int n_in,
                              void* d_out, int out_size, void* d_ws, size_t ws_size,
                              hipStream_t stream)
{
    (void)in_sizes; (void)n_in; (void)out_size; (void)ws_size;
    const float* x       = (const float*)d_in[0];
    const float* h0      = (const float*)d_in[1];
    const float* c0      = (const float*)d_in[2];
    const float* sa_Wih  = (const float*)d_in[3];
    const float* sa_Whh  = (const float*)d_in[4];
    const float* sa_bih  = (const float*)d_in[5];
    const float* sa_bhh  = (const float*)d_in[6];
    const float* m0_Wih  = (const float*)d_in[7];
    const float* m0_Whh  = (const float*)d_in[8];
    const float* m0_bih  = (const float*)d_in[9];
    const float* m0_bhh  = (const float*)d_in[10];
    const float* mL_Wih  = (const float*)d_in[11];
    const float* mL_Whh  = (const float*)d_in[12];
    const float* mL_bih  = (const float*)d_in[13];
    const float* mL_bhh  = (const float*)d_in[14];
    const float* safc1_W = (const float*)d_in[15];
    const float* safc1_b = (const float*)d_in[16];
    const float* safc2_W = (const float*)d_in[17];
    const float* safc2_b = (const float*)d_in[18];
    const float* fc1_W   = (const float*)d_in[19];
    const float* fc1_b   = (const float*)d_in[20];

    char* cur = (char*)d_ws;
    auto alloc = [&](size_t bytes) {
        char* p = cur; cur += (bytes + 255) & ~(size_t)255; return p;
    };
    float* XW   = (float*)alloc((size_t)2 * TB_ * G4_ * 4);
    float* Cst  = (float*)alloc(2 * B_ * H_ * 4);
    float* T1b  = (float*)alloc(2 * B_ * H_ * 4);
    float* Eb   = (float*)alloc(2 * B_ * F_ * 4);
    float* AB   = (float*)alloc(B_ * F_ * 4);
    float* saHf = (float*)alloc(2 * B_ * H_ * 4);
    short* xb   = (short*)alloc((size_t)TB_ * KP_ * 2);
    short* Y0b  = (short*)alloc((size_t)TB_ * 2 * H_ * 2);
    short* Y1b  = (short*)alloc((size_t)TB_ * 2 * H_ * 2);
    short* HB0b = (short*)alloc(2 * B_ * H_ * 2);
    short* HB1b = (short*)alloc(2 * B_ * H_ * 2);
    short* Whb  = (short*)alloc((size_t)2 * G4_ * H_ * 2);
    short* Wihb = (short*)alloc((size_t)2 * G4_ * KP_ * 2);
    short* WihbL= (short*)alloc((size_t)2 * G4_ * 2 * H_ * 2);
    short* fc1b = (short*)alloc((size_t)H_ * 2 * H_ * 2);

    auto cv  = [&](const float* s, short* d, int n) {
        conv_f2b<<<(n + 255) / 256, 256, 0, stream>>>(s, d, n);
    };
    auto g16 = [&](const short* Ap, const short* Bp, float* Cp, int M, int N, int K,
                   const float* b1, const float* b2) {
        gemm_bf16<<<dim3(N / 128, M / 128), 256, 0, stream>>>(Ap, Bp, Cp, M, N, K, b1, b2);
    };
    auto run_phase = [&](short* Yout) {
        for (int s = 0; s < T_; s++) {
            short* Hin  = (s & 1) ? HB1b : HB0b;
            short* Hout = (s & 1) ? HB0b : HB1b;
            lstm_step_mfma<<<dim3(32, 2), 256, 0, stream>>>(XW, Whb, Hin, Hout, Cst, Yout, s);
        }
    };

    cv(fc1_W, fc1b, H_ * 2 * H_);

    // ---- Phase A: SA BiLSTM ----
    cv(sa_Whh, Whb, 2 * G4_ * H_);
    conv_f2b_pad<<<(TB_ * KP_ + 255) / 256, 256, 0, stream>>>(x, xb, TB_, F_, KP_);
    conv_f2b_pad<<<(2 * G4_ * KP_ + 255) / 256, 256, 0, stream>>>(sa_Wih, Wihb, 2 * G4_, F_, KP_);
    init_hc2<<<256, 256, 0, stream>>>(h0, c0, HB0b, Cst);
    for (int d = 0; d < 2; d++)
        g16(xb, Wihb + (size_t)d * G4_ * KP_, XW + (size_t)d * TB_ * G4_,
            TB_, G4_, KP_, sa_bih + d * G4_, sa_bhh + d * G4_);
    run_phase(nullptr);
    conv_b2f<<<256, 256, 0, stream>>>(HB0b, saHf, 2 * B_ * H_);
    gemm_bt<<<dim3(8, 2), 256, 0, stream>>>(saHf, safc1_W, T1b, 2 * B_, H_, H_, safc1_b, 1);
    gemm_bt<<<dim3(2, 2), 256, 0, stream>>>(T1b, safc2_W, Eb, 2 * B_, F_, H_, safc2_b, 2);
    attn_alpha<<<B_, 256, 0, stream>>>(Eb, AB);
    scale_xb<<<(TB_ * KP_ + 255) / 256, 256, 0, stream>>>(x, AB, xb);

    // ---- Phase B: main layer 0 ----
    cv(m0_Whh, Whb, 2 * G4_ * H_);
    conv_f2b_pad<<<(2 * G4_ * KP_ + 255) / 256, 256, 0, stream>>>(m0_Wih, Wihb, 2 * G4_, F_, KP_);
    init_hc2<<<256, 256, 0, stream>>>(h0, c0, HB0b, Cst);
    for (int d = 0; d < 2; d++)
        g16(xb, Wihb + (size_t)d * G4_ * KP_, XW + (size_t)d * TB_ * G4_,
            TB_, G4_, KP_, m0_bih + d * G4_, m0_bhh + d * G4_);
    run_phase(Y0b);

    // ---- Phase C: main layer 1 ----
    cv(mL_Whh, Whb, 2 * G4_ * H_);
    cv(mL_Wih, WihbL, 2 * G4_ * 2 * H_);
    init_hc2<<<256, 256, 0, stream>>>(h0 + 2 * B_ * H_, c0 + 2 * B_ * H_, HB0b, Cst);
    for (int d = 0; d < 2; d++)
        g16(Y0b, WihbL + (size_t)d * G4_ * 2 * H_, XW + (size_t)d * TB_ * G4_,
            TB_, G4_, 2 * H_, mL_bih + d * G4_, mL_bhh + d * G4_);
    run_phase(Y1b);

    // ---- Phase D: main layer 2 ----
    cv(mL_Whh + (size_t)2 * G4_ * H_, Whb, 2 * G4_ * H_);
    cv(mL_Wih + (size_t)2 * G4_ * 2 * H_, WihbL, 2 * G4_ * 2 * H_);
    init_hc2<<<256, 256, 0, stream>>>(h0 + 4 * B_ * H_, c0 + 4 * B_ * H_, HB0b, Cst);
    for (int d = 0; d < 2; d++)
        g16(Y1b, WihbL + (size_t)d * G4_ * 2 * H_, XW + (size_t)d * TB_ * G4_,
            TB_, G4_, 2 * H_, mL_bih + (2 + d) * G4_, mL_bhh + (2 + d) * G4_);
    run_phase(Y0b);

    // ---- FC1 ----
    g16(Y0b, fc1b, (float*)d_out, TB_, H_, 2 * H_, fc1_b, nullptr);
}

// Round 3
// 6152.125 us; speedup vs baseline: 2.8175x; 1.3132x over previous
//
#include <hip/hip_runtime.h>
#include <cstddef>

#define T_  128
#define B_  64
#define F_  75
#define H_  512
#define G4_ 2048
#define TB_ (T_ * B_)
#define KP_ 128   // padded K for F=75 inputs

typedef __bf16 bf16x8 __attribute__((ext_vector_type(8)));
typedef float  f32x4  __attribute__((ext_vector_type(4)));

__device__ __forceinline__ short f2b(float x) {
    union { float f; unsigned u; } v; v.f = x;
    return (short)((v.u + 0x7fffu + ((v.u >> 16) & 1u)) >> 16);
}
__device__ __forceinline__ float b2f(short s) {
    union { float f; unsigned u; } v; v.u = ((unsigned)(unsigned short)s) << 16;
    return v.f;
}
__device__ __forceinline__ void gload16(const void* g, void* l) {
    __builtin_amdgcn_global_load_lds(
        (const __attribute__((address_space(1))) void*)g,
        (__attribute__((address_space(3))) void*)l, 16, 0, 0);
}

// ---------------------------------------------------------------------------
// bf16 MFMA GEMM: C(M,N) fp32 = A_bf16(M,K) @ B_bf16(N,K)^T + bias1 + bias2
// ---------------------------------------------------------------------------
__global__ __launch_bounds__(256) void gemm_bf16(
    const short* __restrict__ A, const short* __restrict__ Bm,
    float* __restrict__ C, int M, int N, int K,
    const float* __restrict__ bias1, const float* __restrict__ bias2)
{
    __shared__ short As[4096];
    __shared__ short Bs[4096];
    const int tid = threadIdx.x;
    const int m_base = blockIdx.y * 128;
    const int n_base = blockIdx.x * 128;
    const int w = tid >> 6, lane = tid & 63;
    const int wm = (w >> 1) * 64, wn = (w & 1) * 64;
    const int lm = lane & 15, q = lane >> 4;

    f32x4 acc[4][4];
#pragma unroll
    for (int i = 0; i < 4; i++)
#pragma unroll
        for (int j = 0; j < 4; j++)
#pragma unroll
            for (int r = 0; r < 4; r++) acc[i][j][r] = 0.f;

    const int s0 = tid, s1 = tid + 256;
    const int r0 = s0 & 127, c0 = s0 >> 7;
    const int r1 = s1 & 127, c1 = s1 >> 7;

    for (int k0 = 0; k0 < K; k0 += 32) {
        __syncthreads();
        gload16(A + (size_t)(m_base + r0) * K + k0 + c0 * 8, &As[s0 * 8]);
        gload16(A + (size_t)(m_base + r1) * K + k0 + c1 * 8, &As[s1 * 8]);
        gload16(Bm + (size_t)(n_base + r0) * K + k0 + c0 * 8, &Bs[s0 * 8]);
        gload16(Bm + (size_t)(n_base + r1) * K + k0 + c1 * 8, &Bs[s1 * 8]);
        __syncthreads();
        bf16x8 af[4], bfv[4];
#pragma unroll
        for (int i = 0; i < 4; i++) {
            af[i]  = *(const bf16x8*)&As[((q * 128) + wm + i * 16 + lm) * 8];
            bfv[i] = *(const bf16x8*)&Bs[((q * 128) + wn + i * 16 + lm) * 8];
        }
#pragma unroll
        for (int i = 0; i < 4; i++)
#pragma unroll
            for (int j = 0; j < 4; j++)
                acc[i][j] = __builtin_amdgcn_mfma_f32_16x16x32_bf16(
                    af[i], bfv[j], acc[i][j], 0, 0, 0);
    }

#pragma unroll
    for (int i = 0; i < 4; i++) {
#pragma unroll
        for (int j = 0; j < 4; j++) {
            const int gm = m_base + wm + i * 16 + q * 4;
            const int gn = n_base + wn + j * 16 + lm;
            float bb = (bias1 ? bias1[gn] : 0.f) + (bias2 ? bias2[gn] : 0.f);
#pragma unroll
            for (int r = 0; r < 4; r++)
                C[(size_t)(gm + r) * N + gn] = acc[i][j][r] + bb;
        }
    }
}

// ---------------------------------------------------------------------------
// Pack Whh (2,4H,H) fp32 into MFMA B-fragment order, bf16:
// Wpk[dir][ub(32)][g(4)][it(16)][lane(64)][8] ;  lane=(q*16+lm)
//   value = Whh[dir][g*512 + ub*16 + lm][it*32 + q*8 + e]
// ---------------------------------------------------------------------------
__global__ __launch_bounds__(256) void pack_whh(
    const float* __restrict__ W, short* __restrict__ Wpk)
{
    int i = blockIdx.x * 256 + threadIdx.x;
    if (i >= 2 * G4_ * H_) return;
    int e = i & 7, lane = (i >> 3) & 63, it = (i >> 9) & 15;
    int g = (i >> 13) & 3, ub = (i >> 15) & 31, dir = (i >> 20) & 1;
    int lm = lane & 15, q = lane >> 4;
    float v = W[((size_t)dir * G4_ + g * H_ + ub * 16 + lm) * H_ + it * 32 + q * 8 + e];
    Wpk[i] = f2b(v);
}

// ---------------------------------------------------------------------------
// Init per phase: Ht buffer0 (A-fragment chunk layout [dir][kc64][row64][8])
// from h0 slice, Cst from c0 slice; optionally zero barrier counters.
// ---------------------------------------------------------------------------
__global__ __launch_bounds__(256) void init_phase(
    const float* __restrict__ h0s, const float* __restrict__ c0s,
    short* __restrict__ Ht, float* __restrict__ Cst,
    unsigned* __restrict__ bar, int zero_bar)
{
    int i = blockIdx.x * 256 + threadIdx.x;
    if (i < 2 * B_ * H_) {
        int u = i & 511, b = (i >> 9) & 63, dir = i >> 15;
        Ht[dir * 32768 + (u >> 3) * 512 + b * 8 + (u & 7)] = f2b(h0s[i]);
        Cst[i] = c0s[i];
    }
    if (zero_bar && i < 2) bar[i] = 0;
}

__global__ __launch_bounds__(256) void ht_to_f32(
    const short* __restrict__ Ht0, float* __restrict__ out)
{
    int i = blockIdx.x * 256 + threadIdx.x;
    if (i < 2 * B_ * H_) {
        int u = i & 511, b = (i >> 9) & 63, dir = i >> 15;
        out[i] = b2f(Ht0[dir * 32768 + (u >> 3) * 512 + b * 8 + (u & 7)]);
    }
}

// ---------------------------------------------------------------------------
// Persistent phase kernel: one launch runs all 128 steps, both dirs.
// grid = 64 blocks (dir = blk>>5, 16 units each), 256 thr.
// Whh slice in LDS (packed B-frags). h ping-pong in global (A-frag layout).
// One device-scope barrier per dir per step.
// ---------------------------------------------------------------------------
__global__ __launch_bounds__(256) void lstm_phase(
    const float* __restrict__ XW,   // (2,T,B,4H) fp32, biases included
    const short* __restrict__ Wpk,  // packed Whh bf16
    short* __restrict__ Ht,         // (2 buf, 2 dir, 64 kc, 64 row, 8) bf16
    float* __restrict__ Cst,        // (2,B,H) fp32
    short* __restrict__ Y,          // (T,B,2H) bf16 or null
    unsigned* __restrict__ bar, int phase)
{
    __shared__ short Ws[32768];     // 64 KB packed weights
    const int blk = blockIdx.x;
    const int dir = blk >> 5, ub = blk & 31, u0 = ub * 16;
    const int tid = threadIdx.x, w = tid >> 6, lane = tid & 63;
    const int lm = lane & 15, q = lane >> 4;

    const short* wsrc = Wpk + (size_t)(dir * 32 + ub) * 32768;
#pragma unroll
    for (int p = 0; p < 16; p++)
        gload16(wsrc + (tid + 256 * p) * 8, &Ws[(tid + 256 * p) * 8]);

    const int b0 = w * 16 + q * 4;       // this lane's batch rows b0..b0+3
    const int u = u0 + lm;               // this lane's hidden unit
    unsigned* mybar = bar + dir;
    const unsigned tbase = (unsigned)phase * 4096u;

    float xw[4][4];
    {
        const int t0 = dir ? (T_ - 1) : 0;
        const float* xp = XW + ((size_t)dir * T_ + t0) * B_ * G4_;
#pragma unroll
        for (int r = 0; r < 4; r++)
#pragma unroll
            for (int g = 0; g < 4; g++)
                xw[r][g] = xp[(size_t)(b0 + r) * G4_ + g * H_ + u];
    }
    __syncthreads();   // Ws resident (syncthreads drains vmcnt)

    for (int s = 0; s < T_; s++) {
        const int t = dir ? (T_ - 1 - s) : s;
        const short* Hcur = Ht + (size_t)((s & 1) * 2 + dir) * 32768;

        f32x4 acc[4];
#pragma unroll
        for (int g = 0; g < 4; g++)
#pragma unroll
            for (int r = 0; r < 4; r++) acc[g][r] = 0.f;

#pragma unroll
        for (int it = 0; it < 16; it++) {
            bf16x8 af = *(const bf16x8*)(Hcur + ((it * 4 + q) * 64 + w * 16 + lm) * 8);
#pragma unroll
            for (int g = 0; g < 4; g++) {
                bf16x8 bv = *(const bf16x8*)&Ws[((g * 16 + it) * 64 + lane) * 8];
                acc[g] = __builtin_amdgcn_mfma_f32_16x16x32_bf16(af, bv, acc[g], 0, 0, 0);
            }
        }

        // prefetch next step's XW (covered by pointwise + barrier)
        float xwn[4][4];
        if (s < T_ - 1) {
            const int tn = dir ? (T_ - 2 - s) : (s + 1);
            const float* xp = XW + ((size_t)dir * T_ + tn) * B_ * G4_;
#pragma unroll
            for (int r = 0; r < 4; r++)
#pragma unroll
                for (int g = 0; g < 4; g++)
                    xwn[r][g] = xp[(size_t)(b0 + r) * G4_ + g * H_ + u];
        }

        short* Hnxt = Ht + (size_t)(((s + 1) & 1) * 2 + dir) * 32768;
#pragma unroll
        for (int r = 0; r < 4; r++) {
            const int b = b0 + r;
            float gi = acc[0][r] + xw[r][0];
            float gf = acc[1][r] + xw[r][1];
            float gg = acc[2][r] + xw[r][2];
            float go = acc[3][r] + xw[r][3];
            float ii = 1.f / (1.f + expf(-gi));
            float ff = 1.f / (1.f + expf(-gf));
            float oo = 1.f / (1.f + expf(-go));
            float tg = tanhf(gg);
            size_t ci = (size_t)dir * B_ * H_ + (size_t)b * H_ + u;
            float c = ff * Cst[ci] + ii * tg;
            Cst[ci] = c;
            float h = oo * tanhf(c);
            Hnxt[(u >> 3) * 512 + b * 8 + (u & 7)] = f2b(h);
            if (Y) Y[((size_t)t * B_ + b) * (2 * H_) + dir * H_ + u] = f2b(h);
        }
        if (s < T_ - 1) {
#pragma unroll
            for (int r = 0; r < 4; r++)
#pragma unroll
                for (int g = 0; g < 4; g++) xw[r][g] = xwn[r][g];
        }

        // ---- device-scope barrier among this dir's 32 blocks ----
        __syncthreads();
        if (tid == 0) {
            __threadfence();   // release: h publish visible device-wide
            __hip_atomic_fetch_add(mybar, 1u, __ATOMIC_ACQ_REL, __HIP_MEMORY_SCOPE_AGENT);
            const unsigned tgt = tbase + (unsigned)(s + 1) * 32u;
            while (__hip_atomic_load(mybar, __ATOMIC_RELAXED, __HIP_MEMORY_SCOPE_AGENT) < tgt) {
                __builtin_amdgcn_s_sleep(1);
            }
        }
        __syncthreads();
        __builtin_amdgcn_fence(__ATOMIC_ACQUIRE, "agent");  // invalidate stale caches
    }
}

// ---------------------------------------------------------------------------
// fp32 GEMM for tiny attention matmuls (bounds-checked), act 0/1/2
// ---------------------------------------------------------------------------
__global__ __launch_bounds__(256) void gemm_bt(
    const float* __restrict__ A, const float* __restrict__ Bm,
    float* __restrict__ C, int M, int N, int K,
    const float* __restrict__ bias1, int act)
{
    __shared__ float As[16][68];
    __shared__ float Bs[16][68];
    const int tid = threadIdx.x;
    const int m_base = blockIdx.y * 64;
    const int n_base = blockIdx.x * 64;
    const int tm = tid >> 4, tn = tid & 15;
    float acc[4][4] = {};

    for (int k0 = 0; k0 < K; k0 += 16) {
#pragma unroll
        for (int i = 0; i < 4; i++) {
            int idx = tid * 4 + i;
            int r = idx >> 4, kk = idx & 15;
            int gm = m_base + r, gk = k0 + kk;
            As[kk][r] = (gm < M && gk < K) ? A[(size_t)gm * K + gk] : 0.f;
            int gn = n_base + r;
            Bs[kk][r] = (gn < N && gk < K) ? Bm[(size_t)gn * K + gk] : 0.f;
        }
        __syncthreads();
#pragma unroll
        for (int kk = 0; kk < 16; kk++) {
            float4 av = *(const float4*)&As[kk][tm * 4];
            float4 bv = *(const float4*)&Bs[kk][tn * 4];
            float a[4] = {av.x, av.y, av.z, av.w};
            float b[4] = {bv.x, bv.y, bv.z, bv.w};
#pragma unroll
            for (int i = 0; i < 4; i++)
#pragma unroll
                for (int j = 0; j < 4; j++)
                    acc[i][j] = fmaf(a[i], b[j], acc[i][j]);
        }
        __syncthreads();
    }
#pragma unroll
    for (int i = 0; i < 4; i++) {
        int gm = m_base + tm * 4 + i;
        if (gm >= M) continue;
#pragma unroll
        for (int j = 0; j < 4; j++) {
            int gn = n_base + tn * 4 + j;
            if (gn >= N) continue;
            float v = acc[i][j];
            if (bias1) v += bias1[gn];
            if (act == 1) v = tanhf(v);
            else if (act == 2) v = expf(v);
            C[(size_t)gm * N + gn] = v;
        }
    }
}

// ---------------------------------------------------------------------------
__global__ __launch_bounds__(256) void conv_f2b(
    const float* __restrict__ src, short* __restrict__ dst, int n)
{
    int i = blockIdx.x * 256 + threadIdx.x;
    if (i < n) dst[i] = f2b(src[i]);
}
__global__ __launch_bounds__(256) void conv_f2b_pad(
    const float* __restrict__ src, short* __restrict__ dst,
    int rows, int kin, int kp)
{
    int i = blockIdx.x * 256 + threadIdx.x;
    if (i < rows * kp) {
        int r = i / kp, k = i % kp;
        dst[i] = (k < kin) ? f2b(src[(size_t)r * kin + k]) : (short)0;
    }
}

__global__ __launch_bounds__(256) void attn_alpha(
    const float* __restrict__ E, float* __restrict__ AB)
{
    const int b = blockIdx.x, tid = threadIdx.x;
    __shared__ float red[256];
    __shared__ float adj[152];
    float v = 0.f;
    if (tid < 150) {
        int d = tid / F_, j = tid % F_;
        v = E[((size_t)d * B_ + b) * F_ + j];
    }
    red[tid] = v; __syncthreads();
    for (int s2 = 128; s2 > 0; s2 >>= 1) {
        if (tid < s2) red[tid] += red[tid + s2];
        __syncthreads();
    }
    float total = red[0]; __syncthreads();
    float alpha = v / total;
    float m = (tid < 150 && alpha >= 0.1f) ? 1.f : 0.f;
    red[tid] = m; __syncthreads();
    for (int s2 = 128; s2 > 0; s2 >>= 1) {
        if (tid < s2) red[tid] += red[tid + s2];
        __syncthreads();
    }
    float cnt = red[0]; __syncthreads();
    red[tid] = m * alpha; __syncthreads();
    for (int s2 = 128; s2 > 0; s2 >>= 1) {
        if (tid < s2) red[tid] += red[tid + s2];
        __syncthreads();
    }
    float selsum = red[0]; __syncthreads();
    float selmean = selsum / fmaxf(cnt, 1.f);
    if (tid < 150) adj[tid] = (m > 0.f) ? selmean : alpha;
    __syncthreads();
    if (tid < F_) AB[(size_t)b * F_ + tid] = 0.5f * (adj[tid] + adj[F_ + tid]);
}

__global__ __launch_bounds__(256) void scale_xb(
    const float* __restrict__ x, const float* __restrict__ AB,
    short* __restrict__ xb)
{
    int i = blockIdx.x * 256 + threadIdx.x;
    if (i < TB_ * KP_) {
        int r = i >> 7, k = i & 127;
        if (k < F_) {
            int b = r % B_;
            xb[i] = f2b(x[(size_t)r * F_ + k] * AB[(size_t)b * F_ + k]);
        } else xb[i] = 0;
    }
}

// ---------------------------------------------------------------------------
extern "C" void kernel_launch(void* const* d_in, const int* in_sizes, int n_in,
                              void* d_out, int out_size, void* d_ws, size_t ws_size,
                              hipStream_t stream)
{
    (void)in_sizes; (void)n_in; (void)out_size; (void)ws_size;
    const float* x       = (const float*)d_in[0];
    const float* h0      = (const float*)d_in[1];
    const float* c0      = (const float*)d_in[2];
    const float* sa_Wih  = (const float*)d_in[3];
    const float* sa_Whh  = (const float*)d_in[4];
    const float* sa_bih  = (const float*)d_in[5];
    const float* sa_bhh  = (const float*)d_in[6];
    const float* m0_Wih  = (const float*)d_in[7];
    const float* m0_Whh  = (const float*)d_in[8];
    const float* m0_bih  = (const float*)d_in[9];
    const float* m0_bhh  = (const float*)d_in[10];
    const float* mL_Wih  = (const float*)d_in[11];
    const float* mL_Whh  = (const float*)d_in[12];
    const float* mL_bih  = (const float*)d_in[13];
    const float* mL_bhh  = (const float*)d_in[14];
    const float* safc1_W = (const float*)d_in[15];
    const float* safc1_b = (const float*)d_in[16];
    const float* safc2_W = (const float*)d_in[17];
    const float* safc2_b = (const float*)d_in[18];
    const float* fc1_W   = (const float*)d_in[19];
    const float* fc1_b   = (const float*)d_in[20];

    char* cur = (char*)d_ws;
    auto alloc = [&](size_t bytes) {
        char* p = cur; cur += (bytes + 255) & ~(size_t)255; return p;
    };
    float*    XW   = (float*)alloc((size_t)2 * TB_ * G4_ * 4);
    float*    Cst  = (float*)alloc(2 * B_ * H_ * 4);
    float*    T1b  = (float*)alloc(2 * B_ * H_ * 4);
    float*    Eb   = (float*)alloc(2 * B_ * F_ * 4);
    float*    AB   = (float*)alloc(B_ * F_ * 4);
    float*    saHf = (float*)alloc(2 * B_ * H_ * 4);
    short*    xb   = (short*)alloc((size_t)TB_ * KP_ * 2);
    short*    Y0b  = (short*)alloc((size_t)TB_ * 2 * H_ * 2);
    short*    Y1b  = (short*)alloc((size_t)TB_ * 2 * H_ * 2);
    short*    Ht   = (short*)alloc((size_t)2 * 2 * 64 * 64 * 8 * 2);
    short*    Wpk  = (short*)alloc((size_t)2 * G4_ * H_ * 2);
    short*    Wihb = (short*)alloc((size_t)2 * G4_ * KP_ * 2);
    short*    WihbL= (short*)alloc((size_t)2 * G4_ * 2 * H_ * 2);
    short*    fc1b = (short*)alloc((size_t)H_ * 2 * H_ * 2);
    unsigned* bar  = (unsigned*)alloc(256);

    auto cv = [&](const float* s, short* d, int n) {
        conv_f2b<<<(n + 255) / 256, 256, 0, stream>>>(s, d, n);
    };
    auto g16 = [&](const short* Ap, const short* Bp, float* Cp, int M, int N, int K,
                   const float* b1, const float* b2) {
        gemm_bf16<<<dim3(N / 128, M / 128), 256, 0, stream>>>(Ap, Bp, Cp, M, N, K, b1, b2);
    };
    auto phase = [&](const float* Whh_p, const float* h0p, const float* c0p,
                     short* Yout, int pidx) {
        pack_whh<<<(2 * G4_ * H_ + 255) / 256, 256, 0, stream>>>(Whh_p, Wpk);
        init_phase<<<256, 256, 0, stream>>>(h0p, c0p, Ht, Cst, bar, pidx == 0 ? 1 : 0);
        lstm_phase<<<64, 256, 0, stream>>>(XW, Wpk, Ht, Cst, Yout, bar, pidx);
    };

    cv(fc1_W, fc1b, H_ * 2 * H_);

    // ---- Phase A: SA BiLSTM ----
    conv_f2b_pad<<<(TB_ * KP_ + 255) / 256, 256, 0, stream>>>(x, xb, TB_, F_, KP_);
    conv_f2b_pad<<<(2 * G4_ * KP_ + 255) / 256, 256, 0, stream>>>(sa_Wih, Wihb, 2 * G4_, F_, KP_);
    for (int d = 0; d < 2; d++)
        g16(xb, Wihb + (size_t)d * G4_ * KP_, XW + (size_t)d * TB_ * G4_,
            TB_, G4_, KP_, sa_bih + d * G4_, sa_bhh + d * G4_);
    phase(sa_Whh, h0, c0, nullptr, 0);
    ht_to_f32<<<256, 256, 0, stream>>>(Ht, saHf);   // final h in buffer 0
    gemm_bt<<<dim3(8, 2), 256, 0, stream>>>(saHf, safc1_W, T1b, 2 * B_, H_, H_, safc1_b, 1);
    gemm_bt<<<dim3(2, 2), 256, 0, stream>>>(T1b, safc2_W, Eb, 2 * B_, F_, H_, safc2_b, 2);
    attn_alpha<<<B_, 256, 0, stream>>>(Eb, AB);
    scale_xb<<<(TB_ * KP_ + 255) / 256, 256, 0, stream>>>(x, AB, xb);

    // ---- Phase B: main layer 0 ----
    conv_f2b_pad<<<(2 * G4_ * KP_ + 255) / 256, 256, 0, stream>>>(m0_Wih, Wihb, 2 * G4_, F_, KP_);
    for (int d = 0; d < 2; d++)
        g16(xb, Wihb + (size_t)d * G4_ * KP_, XW + (size_t)d * TB_ * G4_,
            TB_, G4_, KP_, m0_bih + d * G4_, m0_bhh + d * G4_);
    phase(m0_Whh, h0, c0, Y0b, 1);

    // ---- Phase C: main layer 1 ----
    cv(mL_Wih, WihbL, 2 * G4_ * 2 * H_);
    for (int d = 0; d < 2; d++)
        g16(Y0b, WihbL + (size_t)d * G4_ * 2 * H_, XW + (size_t)d * TB_ * G4_,
            TB_, G4_, 2 * H_, mL_bih + d * G4_, mL_bhh + d * G4_);
    phase(mL_Whh, h0 + 2 * B_ * H_, c0 + 2 * B_ * H_, Y1b, 2);

    // ---- Phase D: main layer 2 ----
    cv(mL_Wih + (size_t)2 * G4_ * 2 * H_, WihbL, 2 * G4_ * 2 * H_);
    for (int d = 0; d < 2; d++)
        g16(Y1b, WihbL + (size_t)d * G4_ * 2 * H_, XW + (size_t)d * TB_ * G4_,
            TB_, G4_, 2 * H_, mL_bih + (2 + d) * G4_, mL_bhh + (2 + d) * G4_);
    phase(mL_Whh + (size_t)2 * G4_ * H_, h0 + 4 * B_ * H_, c0 + 4 * B_ * H_, Y0b, 3);

    // ---- FC1 ----
    g16(Y0b, fc1b, (float*)d_out, TB_, H_, 2 * H_, fc1_b, nullptr);
}

// Round 4
// 5427.233 us; speedup vs baseline: 3.1939x; 1.1336x over previous
//
#include <hip/hip_runtime.h>
#include <cstddef>

#define T_  128
#define B_  64
#define F_  75
#define H_  512
#define G4_ 2048
#define TB_ (T_ * B_)
#define KP_ 128   // padded K for F=75 inputs

typedef __bf16 bf16x8 __attribute__((ext_vector_type(8)));
typedef float  f32x4  __attribute__((ext_vector_type(4)));
typedef unsigned long long u64;

__device__ __forceinline__ short f2b(float x) {
    union { float f; unsigned u; } v; v.f = x;
    return (short)((v.u + 0x7fffu + ((v.u >> 16) & 1u)) >> 16);
}
__device__ __forceinline__ float b2f(short s) {
    union { float f; unsigned u; } v; v.u = ((unsigned)(unsigned short)s) << 16;
    return v.f;
}
__device__ __forceinline__ void gload16(const void* g, void* l) {
    __builtin_amdgcn_global_load_lds(
        (const __attribute__((address_space(1))) void*)g,
        (__attribute__((address_space(3))) void*)l, 16, 0, 0);
}
// fast sigmoid/tanh via v_exp_f32 + v_rcp_f32 (error ~1e-6, irrelevant vs bf16)
__device__ __forceinline__ float fsig(float x) {
    return __builtin_amdgcn_rcpf(1.f + __expf(-x));
}
__device__ __forceinline__ float ftanh(float x) {
    return 1.f - 2.f * __builtin_amdgcn_rcpf(1.f + __expf(2.f * x));
}

// ---------------------------------------------------------------------------
// bf16 MFMA GEMM: C(M,N) fp32 = A_bf16(M,K) @ B_bf16(N,K)^T + bias1 + bias2
// ---------------------------------------------------------------------------
__global__ __launch_bounds__(256) void gemm_bf16(
    const short* __restrict__ A, const short* __restrict__ Bm,
    float* __restrict__ C, int M, int N, int K,
    const float* __restrict__ bias1, const float* __restrict__ bias2)
{
    __shared__ short As[4096];
    __shared__ short Bs[4096];
    const int tid = threadIdx.x;
    const int m_base = blockIdx.y * 128;
    const int n_base = blockIdx.x * 128;
    const int w = tid >> 6, lane = tid & 63;
    const int wm = (w >> 1) * 64, wn = (w & 1) * 64;
    const int lm = lane & 15, q = lane >> 4;

    f32x4 acc[4][4];
#pragma unroll
    for (int i = 0; i < 4; i++)
#pragma unroll
        for (int j = 0; j < 4; j++)
#pragma unroll
            for (int r = 0; r < 4; r++) acc[i][j][r] = 0.f;

    const int s0 = tid, s1 = tid + 256;
    const int r0 = s0 & 127, c0 = s0 >> 7;
    const int r1 = s1 & 127, c1 = s1 >> 7;

    for (int k0 = 0; k0 < K; k0 += 32) {
        __syncthreads();
        gload16(A + (size_t)(m_base + r0) * K + k0 + c0 * 8, &As[s0 * 8]);
        gload16(A + (size_t)(m_base + r1) * K + k0 + c1 * 8, &As[s1 * 8]);
        gload16(Bm + (size_t)(n_base + r0) * K + k0 + c0 * 8, &Bs[s0 * 8]);
        gload16(Bm + (size_t)(n_base + r1) * K + k0 + c1 * 8, &Bs[s1 * 8]);
        __syncthreads();
        bf16x8 af[4], bfv[4];
#pragma unroll
        for (int i = 0; i < 4; i++) {
            af[i]  = *(const bf16x8*)&As[((q * 128) + wm + i * 16 + lm) * 8];
            bfv[i] = *(const bf16x8*)&Bs[((q * 128) + wn + i * 16 + lm) * 8];
        }
#pragma unroll
        for (int i = 0; i < 4; i++)
#pragma unroll
            for (int j = 0; j < 4; j++)
                acc[i][j] = __builtin_amdgcn_mfma_f32_16x16x32_bf16(
                    af[i], bfv[j], acc[i][j], 0, 0, 0);
    }

#pragma unroll
    for (int i = 0; i < 4; i++) {
#pragma unroll
        for (int j = 0; j < 4; j++) {
            const int gm = m_base + wm + i * 16 + q * 4;
            const int gn = n_base + wn + j * 16 + lm;
            float bb = (bias1 ? bias1[gn] : 0.f) + (bias2 ? bias2[gn] : 0.f);
#pragma unroll
            for (int r = 0; r < 4; r++)
                C[(size_t)(gm + r) * N + gn] = acc[i][j][r] + bb;
        }
    }
}

// ---------------------------------------------------------------------------
// Pack Whh (2,4H,H) fp32 -> bf16 B-fragments:
// Wpk[dir][ub(16)][ug(2)][g(4)][it(16)][lane(64)][8]
//   = Whh[dir][g*512 + ub*32 + ug*16 + (lane&15)][it*32 + (lane>>4)*8 + e]
// ---------------------------------------------------------------------------
__global__ __launch_bounds__(256) void pack_whh(
    const float* __restrict__ W, short* __restrict__ Wpk)
{
    int i = blockIdx.x * 256 + threadIdx.x;
    if (i >= 2 * G4_ * H_) return;
    int e = i & 7, lane = (i >> 3) & 63, it = (i >> 9) & 15;
    int g = (i >> 13) & 3, ug = (i >> 15) & 1, ub = (i >> 16) & 15, dir = (i >> 20) & 1;
    int lm = lane & 15, qq = lane >> 4;
    float v = W[((size_t)dir * G4_ + g * H_ + ub * 32 + ug * 16 + lm) * H_
                + it * 32 + qq * 8 + e];
    Wpk[i] = f2b(v);
}

// ---------------------------------------------------------------------------
// Init: Ht buf0 [dir][b][u] = h0 (linear match), zero barrier slots.
// ---------------------------------------------------------------------------
__global__ __launch_bounds__(256) void init_phase(
    const float* __restrict__ h0s, short* __restrict__ Ht,
    unsigned* __restrict__ bar, int zero_bar)
{
    int i = blockIdx.x * 256 + threadIdx.x;
    if (i < 2 * B_ * H_) Ht[i] = f2b(h0s[i]);
    if (zero_bar && i < 64) bar[i] = 0;
}

__global__ __launch_bounds__(256) void ht_to_f32(
    const short* __restrict__ Ht0, float* __restrict__ out)
{
    int i = blockIdx.x * 256 + threadIdx.x;
    if (i < 2 * B_ * H_) out[i] = b2f(Ht0[i]);
}

// ---------------------------------------------------------------------------
// Persistent fence-free phase kernel. grid (16, 2): block = 32 units, 1 dir.
// Whh in 128KB LDS. h exchanged via L3 (agent-scope relaxed atomics, no
// cache-maintenance fences). c-state in registers. Slot-store barrier.
// ---------------------------------------------------------------------------
__global__ __launch_bounds__(256, 1) void lstm_phase(
    const float* __restrict__ XW,   // (2,T,B,4H) fp32, biases included
    const short* __restrict__ Wpk,  // packed Whh bf16
    short* __restrict__ Ht,         // (2buf,2dir,64b,512u) bf16
    const float* __restrict__ c0p,  // (2,B,H) fp32 initial c
    short* __restrict__ Y,          // (T,B,2H) bf16 or null
    unsigned* __restrict__ bar, int phase)
{
    __shared__ short Ws[65536];     // 128 KB packed weights
    __shared__ short Tb[64 * 36];   // transpose buffer (pad 36 vs 32)
    const int dir = blockIdx.y, ub = blockIdx.x, u0 = ub * 32;
    const int tid = threadIdx.x, w = tid >> 6, lane = tid & 63;
    const int lm = lane & 15, q = lane >> 4;

    const short* wsrc = Wpk + ((size_t)(dir * 16 + ub) << 16);
#pragma unroll
    for (int p = 0; p < 32; p++)
        gload16(wsrc + (tid + 256 * p) * 8, &Ws[(tid + 256 * p) * 8]);

    const int b0 = w * 16 + q * 4;   // this lane's 4 batch rows
    unsigned* slots = bar + dir * 16;

    float c[2][4];
    float xw[2][4][4];
#pragma unroll
    for (int ug = 0; ug < 2; ug++)
#pragma unroll
        for (int r = 0; r < 4; r++)
            c[ug][r] = c0p[(size_t)dir * B_ * H_ + (size_t)(b0 + r) * H_
                           + u0 + ug * 16 + lm];
    {
        const int t0 = dir ? (T_ - 1) : 0;
        const float* xp = XW + ((size_t)dir * T_ + t0) * B_ * G4_;
#pragma unroll
        for (int ug = 0; ug < 2; ug++)
#pragma unroll
            for (int r = 0; r < 4; r++)
#pragma unroll
                for (int g = 0; g < 4; g++)
                    xw[ug][r][g] = xp[(size_t)(b0 + r) * G4_ + g * H_
                                      + u0 + ug * 16 + lm];
    }
    __syncthreads();   // Ws resident (barrier drains global_load_lds)

    for (int s = 0; s < T_; s++) {
        const int t = dir ? (T_ - 1 - s) : s;
        const short* Hc = Ht + ((size_t)((s & 1) * 2 + dir) << 15);

        // ---- h fragments: [b=w*16+lm][k=it*32+q*8..+7], L2-bypassing loads
        u64 hq[32];
#pragma unroll
        for (int it = 0; it < 16; it++) {
            const u64* hp = (const u64*)(Hc + (w * 16 + lm) * 512 + it * 32 + q * 8);
            hq[2 * it]     = __hip_atomic_load((u64*)hp,     __ATOMIC_RELAXED, __HIP_MEMORY_SCOPE_AGENT);
            hq[2 * it + 1] = __hip_atomic_load((u64*)hp + 1, __ATOMIC_RELAXED, __HIP_MEMORY_SCOPE_AGENT);
        }

        f32x4 acc[2][4];
#pragma unroll
        for (int ug = 0; ug < 2; ug++)
#pragma unroll
            for (int g = 0; g < 4; g++)
#pragma unroll
                for (int r = 0; r < 4; r++) acc[ug][g][r] = 0.f;

#pragma unroll
        for (int it = 0; it < 16; it++) {
            union { u64 q2[2]; bf16x8 v; } ua;
            ua.q2[0] = hq[2 * it]; ua.q2[1] = hq[2 * it + 1];
#pragma unroll
            for (int ug = 0; ug < 2; ug++)
#pragma unroll
                for (int g = 0; g < 4; g++) {
                    bf16x8 bv = *(const bf16x8*)&Ws[(((ug * 4 + g) * 16 + it) * 64 + lane) * 8];
                    acc[ug][g] = __builtin_amdgcn_mfma_f32_16x16x32_bf16(
                        ua.v, bv, acc[ug][g], 0, 0, 0);
                }
        }

        // ---- pointwise gates; h -> LDS transpose tile
#pragma unroll
        for (int ug = 0; ug < 2; ug++)
#pragma unroll
            for (int r = 0; r < 4; r++) {
                float gi = acc[ug][0][r] + xw[ug][r][0];
                float gf = acc[ug][1][r] + xw[ug][r][1];
                float gg = acc[ug][2][r] + xw[ug][r][2];
                float go = acc[ug][3][r] + xw[ug][r][3];
                float cc = fsig(gf) * c[ug][r] + fsig(gi) * ftanh(gg);
                c[ug][r] = cc;
                float h = fsig(go) * ftanh(cc);
                Tb[(b0 + r) * 36 + ug * 16 + lm] = f2b(h);
            }
        __syncthreads();

        // ---- coalesced writeout: thread -> (b = tid>>2, u-quad = tid&3)
        {
            const int b = tid >> 2, qd = tid & 3;
            u64 v0 = *(const u64*)&Tb[b * 36 + qd * 8];
            u64 v1 = *(const u64*)&Tb[b * 36 + qd * 8 + 4];
            short* Hn = Ht + ((size_t)(((s + 1) & 1) * 2 + dir) << 15);
            u64* hp = (u64*)(Hn + b * 512 + u0 + qd * 8);
            __hip_atomic_store(hp,     v0, __ATOMIC_RELAXED, __HIP_MEMORY_SCOPE_AGENT);
            __hip_atomic_store(hp + 1, v1, __ATOMIC_RELAXED, __HIP_MEMORY_SCOPE_AGENT);
            if (Y) {
                u64* yp = (u64*)(Y + ((size_t)t * B_ + b) * (2 * H_) + dir * H_ + u0 + qd * 8);
                yp[0] = v0; yp[1] = v1;
            }
        }
        __builtin_amdgcn_s_waitcnt(0);   // drain h stores (belt & braces)
        __syncthreads();                 // all waves' stores complete

        const unsigned tgt = (unsigned)(phase * T_ + s + 1);
        if (tid == 0)
            __hip_atomic_store(&slots[ub], tgt, __ATOMIC_RELAXED, __HIP_MEMORY_SCOPE_AGENT);

        // prefetch next step's XW during the spin
        if (s < T_ - 1) {
            const int tn = dir ? (T_ - 2 - s) : (s + 1);
            const float* xp = XW + ((size_t)dir * T_ + tn) * B_ * G4_;
#pragma unroll
            for (int ug = 0; ug < 2; ug++)
#pragma unroll
                for (int r = 0; r < 4; r++)
#pragma unroll
                    for (int g = 0; g < 4; g++)
                        xw[ug][r][g] = xp[(size_t)(b0 + r) * G4_ + g * H_
                                          + u0 + ug * 16 + lm];
        }
        if (tid < 16) {
            while (__hip_atomic_load(&slots[tid], __ATOMIC_RELAXED, __HIP_MEMORY_SCOPE_AGENT) < tgt)
                __builtin_amdgcn_s_sleep(1);
        }
        __syncthreads();
    }
}

// ---------------------------------------------------------------------------
// fp32 GEMM for tiny attention matmuls (bounds-checked), act 0/1/2
// ---------------------------------------------------------------------------
__global__ __launch_bounds__(256) void gemm_bt(
    const float* __restrict__ A, const float* __restrict__ Bm,
    float* __restrict__ C, int M, int N, int K,
    const float* __restrict__ bias1, int act)
{
    __shared__ float As[16][68];
    __shared__ float Bs[16][68];
    const int tid = threadIdx.x;
    const int m_base = blockIdx.y * 64;
    const int n_base = blockIdx.x * 64;
    const int tm = tid >> 4, tn = tid & 15;
    float acc[4][4] = {};

    for (int k0 = 0; k0 < K; k0 += 16) {
#pragma unroll
        for (int i = 0; i < 4; i++) {
            int idx = tid * 4 + i;
            int r = idx >> 4, kk = idx & 15;
            int gm = m_base + r, gk = k0 + kk;
            As[kk][r] = (gm < M && gk < K) ? A[(size_t)gm * K + gk] : 0.f;
            int gn = n_base + r;
            Bs[kk][r] = (gn < N && gk < K) ? Bm[(size_t)gn * K + gk] : 0.f;
        }
        __syncthreads();
#pragma unroll
        for (int kk = 0; kk < 16; kk++) {
            float4 av = *(const float4*)&As[kk][tm * 4];
            float4 bv = *(const float4*)&Bs[kk][tn * 4];
            float a[4] = {av.x, av.y, av.z, av.w};
            float b[4] = {bv.x, bv.y, bv.z, bv.w};
#pragma unroll
            for (int i = 0; i < 4; i++)
#pragma unroll
                for (int j = 0; j < 4; j++)
                    acc[i][j] = fmaf(a[i], b[j], acc[i][j]);
        }
        __syncthreads();
    }
#pragma unroll
    for (int i = 0; i < 4; i++) {
        int gm = m_base + tm * 4 + i;
        if (gm >= M) continue;
#pragma unroll
        for (int j = 0; j < 4; j++) {
            int gn = n_base + tn * 4 + j;
            if (gn >= N) continue;
            float v = acc[i][j];
            if (bias1) v += bias1[gn];
            if (act == 1) v = tanhf(v);
            else if (act == 2) v = expf(v);
            C[(size_t)gm * N + gn] = v;
        }
    }
}

// ---------------------------------------------------------------------------
__global__ __launch_bounds__(256) void conv_f2b(
    const float* __restrict__ src, short* __restrict__ dst, int n)
{
    int i = blockIdx.x * 256 + threadIdx.x;
    if (i < n) dst[i] = f2b(src[i]);
}
__global__ __launch_bounds__(256) void conv_f2b_pad(
    const float* __restrict__ src, short* __restrict__ dst,
    int rows, int kin, int kp)
{
    int i = blockIdx.x * 256 + threadIdx.x;
    if (i < rows * kp) {
        int r = i / kp, k = i % kp;
        dst[i] = (k < kin) ? f2b(src[(size_t)r * kin + k]) : (short)0;
    }
}

__global__ __launch_bounds__(256) void attn_alpha(
    const float* __restrict__ E, float* __restrict__ AB)
{
    const int b = blockIdx.x, tid = threadIdx.x;
    __shared__ float red[256];
    __shared__ float adj[152];
    float v = 0.f;
    if (tid < 150) {
        int d = tid / F_, j = tid % F_;
        v = E[((size_t)d * B_ + b) * F_ + j];
    }
    red[tid] = v; __syncthreads();
    for (int s2 = 128; s2 > 0; s2 >>= 1) {
        if (tid < s2) red[tid] += red[tid + s2];
        __syncthreads();
    }
    float total = red[0]; __syncthreads();
    float alpha = v / total;
    float m = (tid < 150 && alpha >= 0.1f) ? 1.f : 0.f;
    red[tid] = m; __syncthreads();
    for (int s2 = 128; s2 > 0; s2 >>= 1) {
        if (tid < s2) red[tid] += red[tid + s2];
        __syncthreads();
    }
    float cnt = red[0]; __syncthreads();
    red[tid] = m * alpha; __syncthreads();
    for (int s2 = 128; s2 > 0; s2 >>= 1) {
        if (tid < s2) red[tid] += red[tid + s2];
        __syncthreads();
    }
    float selsum = red[0]; __syncthreads();
    float selmean = selsum / fmaxf(cnt, 1.f);
    if (tid < 150) adj[tid] = (m > 0.f) ? selmean : alpha;
    __syncthreads();
    if (tid < F_) AB[(size_t)b * F_ + tid] = 0.5f * (adj[tid] + adj[F_ + tid]);
}

__global__ __launch_bounds__(256) void scale_xb(
    const float* __restrict__ x, const float* __restrict__ AB,
    short* __restrict__ xb)
{
    int i = blockIdx.x * 256 + threadIdx.x;
    if (i < TB_ * KP_) {
        int r = i >> 7, k = i & 127;
        if (k < F_) {
            int b = r % B_;
            xb[i] = f2b(x[(size_t)r * F_ + k] * AB[(size_t)b * F_ + k]);
        } else xb[i] = 0;
    }
}

// ---------------------------------------------------------------------------
extern "C" void kernel_launch(void* const* d_in, const int* in_sizes, int n_in,
                              void* d_out, int out_size, void* d_ws, size_t ws_size,
                              hipStream_t stream)
{
    (void)in_sizes; (void)n_in; (void)out_size; (void)ws_size;
    const float* x       = (const float*)d_in[0];
    const float* h0      = (const float*)d_in[1];
    const float* c0      = (const float*)d_in[2];
    const float* sa_Wih  = (const float*)d_in[3];
    const float* sa_Whh  = (const float*)d_in[4];
    const float* sa_bih  = (const float*)d_in[5];
    const float* sa_bhh  = (const float*)d_in[6];
    const float* m0_Wih  = (const float*)d_in[7];
    const float* m0_Whh  = (const float*)d_in[8];
    const float* m0_bih  = (const float*)d_in[9];
    const float* m0_bhh  = (const float*)d_in[10];
    const float* mL_Wih  = (const float*)d_in[11];
    const float* mL_Whh  = (const float*)d_in[12];
    const float* mL_bih  = (const float*)d_in[13];
    const float* mL_bhh  = (const float*)d_in[14];
    const float* safc1_W = (const float*)d_in[15];
    const float* safc1_b = (const float*)d_in[16];
    const float* safc2_W = (const float*)d_in[17];
    const float* safc2_b = (const float*)d_in[18];
    const float* fc1_W   = (const float*)d_in[19];
    const float* fc1_b   = (const float*)d_in[20];

    char* cur = (char*)d_ws;
    auto alloc = [&](size_t bytes) {
        char* p = cur; cur += (bytes + 255) & ~(size_t)255; return p;
    };
    float*    XW   = (float*)alloc((size_t)2 * TB_ * G4_ * 4);
    float*    T1b  = (float*)alloc(2 * B_ * H_ * 4);
    float*    Eb   = (float*)alloc(2 * B_ * F_ * 4);
    float*    AB   = (float*)alloc(B_ * F_ * 4);
    float*    saHf = (float*)alloc(2 * B_ * H_ * 4);
    short*    xb   = (short*)alloc((size_t)TB_ * KP_ * 2);
    short*    Y0b  = (short*)alloc((size_t)TB_ * 2 * H_ * 2);
    short*    Y1b  = (short*)alloc((size_t)TB_ * 2 * H_ * 2);
    short*    Ht   = (short*)alloc((size_t)2 * 2 * B_ * H_ * 2);
    short*    Wpk  = (short*)alloc((size_t)2 * G4_ * H_ * 2);
    short*    Wihb = (short*)alloc((size_t)2 * G4_ * KP_ * 2);
    short*    WihbL= (short*)alloc((size_t)2 * G4_ * 2 * H_ * 2);
    short*    fc1b = (short*)alloc((size_t)H_ * 2 * H_ * 2);
    unsigned* bar  = (unsigned*)alloc(256);

    auto cv = [&](const float* s, short* d, int n) {
        conv_f2b<<<(n + 255) / 256, 256, 0, stream>>>(s, d, n);
    };
    auto g16 = [&](const short* Ap, const short* Bp, float* Cp, int M, int N, int K,
                   const float* b1, const float* b2) {
        gemm_bf16<<<dim3(N / 128, M / 128), 256, 0, stream>>>(Ap, Bp, Cp, M, N, K, b1, b2);
    };
    auto phase = [&](const float* Whh_p, const float* h0p, const float* c0p,
                     short* Yout, int pidx) {
        pack_whh<<<(2 * G4_ * H_ + 255) / 256, 256, 0, stream>>>(Whh_p, Wpk);
        init_phase<<<256, 256, 0, stream>>>(h0p, Ht, bar, pidx == 0 ? 1 : 0);
        lstm_phase<<<dim3(16, 2), 256, 0, stream>>>(XW, Wpk, Ht, c0p, Yout, bar, pidx);
    };

    cv(fc1_W, fc1b, H_ * 2 * H_);

    // ---- Phase A: SA BiLSTM ----
    conv_f2b_pad<<<(TB_ * KP_ + 255) / 256, 256, 0, stream>>>(x, xb, TB_, F_, KP_);
    conv_f2b_pad<<<(2 * G4_ * KP_ + 255) / 256, 256, 0, stream>>>(sa_Wih, Wihb, 2 * G4_, F_, KP_);
    for (int d = 0; d < 2; d++)
        g16(xb, Wihb + (size_t)d * G4_ * KP_, XW + (size_t)d * TB_ * G4_,
            TB_, G4_, KP_, sa_bih + d * G4_, sa_bhh + d * G4_);
    phase(sa_Whh, h0, c0, nullptr, 0);
    ht_to_f32<<<256, 256, 0, stream>>>(Ht, saHf);   // final h in buffer 0
    gemm_bt<<<dim3(8, 2), 256, 0, stream>>>(saHf, safc1_W, T1b, 2 * B_, H_, H_, safc1_b, 1);
    gemm_bt<<<dim3(2, 2), 256, 0, stream>>>(T1b, safc2_W, Eb, 2 * B_, F_, H_, safc2_b, 2);
    attn_alpha<<<B_, 256, 0, stream>>>(Eb, AB);
    scale_xb<<<(TB_ * KP_ + 255) / 256, 256, 0, stream>>>(x, AB, xb);

    // ---- Phase B: main layer 0 ----
    conv_f2b_pad<<<(2 * G4_ * KP_ + 255) / 256, 256, 0, stream>>>(m0_Wih, Wihb, 2 * G4_, F_, KP_);
    for (int d = 0; d < 2; d++)
        g16(xb, Wihb + (size_t)d * G4_ * KP_, XW + (size_t)d * TB_ * G4_,
            TB_, G4_, KP_, m0_bih + d * G4_, m0_bhh + d * G4_);
    phase(m0_Whh, h0, c0, Y0b, 1);

    // ---- Phase C: main layer 1 ----
    cv(mL_Wih, WihbL, 2 * G4_ * 2 * H_);
    for (int d = 0; d < 2; d++)
        g16(Y0b, WihbL + (size_t)d * G4_ * 2 * H_, XW + (size_t)d * TB_ * G4_,
            TB_, G4_, 2 * H_, mL_bih + d * G4_, mL_bhh + d * G4_);
    phase(mL_Whh, h0 + 2 * B_ * H_, c0 + 2 * B_ * H_, Y1b, 2);

    // ---- Phase D: main layer 2 ----
    cv(mL_Wih + (size_t)2 * G4_ * 2 * H_, WihbL, 2 * G4_ * 2 * H_);
    for (int d = 0; d < 2; d++)
        g16(Y1b, WihbL + (size_t)d * G4_ * 2 * H_, XW + (size_t)d * TB_ * G4_,
            TB_, G4_, 2 * H_, mL_bih + (2 + d) * G4_, mL_bhh + (2 + d) * G4_);
    phase(mL_Whh + (size_t)2 * G4_ * H_, h0 + 4 * B_ * H_, c0 + 4 * B_ * H_, Y0b, 3);

    // ---- FC1 ----
    g16(Y0b, fc1b, (float*)d_out, TB_, H_, 2 * H_, fc1_b, nullptr);
}

// Round 5
// 4214.441 us; speedup vs baseline: 4.1130x; 1.2878x over previous
//
#include <hip/hip_runtime.h>
#include <cstddef>

#define T_  128
#define B_  64
#define F_  75
#define H_  512
#define G4_ 2048
#define TB_ (T_ * B_)
#define KP_ 128   // padded K for F=75 inputs

typedef __bf16 bf16x8 __attribute__((ext_vector_type(8)));
typedef float  f32x4  __attribute__((ext_vector_type(4)));
typedef unsigned long long u64;

__device__ __forceinline__ short f2b(float x) {
    union { float f; unsigned u; } v; v.f = x;
    return (short)((v.u + 0x7fffu + ((v.u >> 16) & 1u)) >> 16);
}
__device__ __forceinline__ float b2f(short s) {
    union { float f; unsigned u; } v; v.u = ((unsigned)(unsigned short)s) << 16;
    return v.f;
}
__device__ __forceinline__ void gload16(const void* g, void* l) {
    __builtin_amdgcn_global_load_lds(
        (const __attribute__((address_space(1))) void*)g,
        (__attribute__((address_space(3))) void*)l, 16, 0, 0);
}
__device__ __forceinline__ float fsig(float x) {
    return __builtin_amdgcn_rcpf(1.f + __expf(-x));
}
__device__ __forceinline__ float ftanh(float x) {
    return 1.f - 2.f * __builtin_amdgcn_rcpf(1.f + __expf(2.f * x));
}

// ---------------------------------------------------------------------------
// bf16 MFMA GEMM. If P != null: write fp32 results into the step-kernel's
// packed XW layout  P[t][ub(32)][r(4)][tidS(256)][g(4)]  (biases included).
// Else: C(M,N) fp32 row-major.
// ---------------------------------------------------------------------------
__global__ __launch_bounds__(256) void gemm_bf16(
    const short* __restrict__ A, const short* __restrict__ Bm,
    float* __restrict__ C, float* __restrict__ P, int M, int N, int K,
    const float* __restrict__ bias1, const float* __restrict__ bias2)
{
    __shared__ short As[4096];
    __shared__ short Bs[4096];
    const int tid = threadIdx.x;
    const int m_base = blockIdx.y * 128;
    const int n_base = blockIdx.x * 128;
    const int w = tid >> 6, lane = tid & 63;
    const int wm = (w >> 1) * 64, wn = (w & 1) * 64;
    const int lm = lane & 15, q = lane >> 4;

    f32x4 acc[4][4];
#pragma unroll
    for (int i = 0; i < 4; i++)
#pragma unroll
        for (int j = 0; j < 4; j++)
#pragma unroll
            for (int r = 0; r < 4; r++) acc[i][j][r] = 0.f;

    const int s0 = tid, s1 = tid + 256;
    const int r0 = s0 & 127, c0 = s0 >> 7;
    const int r1 = s1 & 127, c1 = s1 >> 7;

    for (int k0 = 0; k0 < K; k0 += 32) {
        __syncthreads();
        gload16(A + (size_t)(m_base + r0) * K + k0 + c0 * 8, &As[s0 * 8]);
        gload16(A + (size_t)(m_base + r1) * K + k0 + c1 * 8, &As[s1 * 8]);
        gload16(Bm + (size_t)(n_base + r0) * K + k0 + c0 * 8, &Bs[s0 * 8]);
        gload16(Bm + (size_t)(n_base + r1) * K + k0 + c1 * 8, &Bs[s1 * 8]);
        __syncthreads();
        bf16x8 af[4], bfv[4];
#pragma unroll
        for (int i = 0; i < 4; i++) {
            af[i]  = *(const bf16x8*)&As[((q * 128) + wm + i * 16 + lm) * 8];
            bfv[i] = *(const bf16x8*)&Bs[((q * 128) + wn + i * 16 + lm) * 8];
        }
#pragma unroll
        for (int i = 0; i < 4; i++)
#pragma unroll
            for (int j = 0; j < 4; j++)
                acc[i][j] = __builtin_amdgcn_mfma_f32_16x16x32_bf16(
                    af[i], bfv[j], acc[i][j], 0, 0, 0);
    }

#pragma unroll
    for (int i = 0; i < 4; i++) {
#pragma unroll
        for (int j = 0; j < 4; j++) {
            const int gm0 = m_base + wm + i * 16 + q * 4;
            const int gn = n_base + wn + j * 16 + lm;
            float bb = (bias1 ? bias1[gn] : 0.f) + (bias2 ? bias2[gn] : 0.f);
            if (P) {
                const int g = gn >> 9, u = gn & 511;
                const int ub = u >> 4, lmu = u & 15;
#pragma unroll
                for (int r = 0; r < 4; r++) {
                    const int gm = gm0 + r;
                    const int t = gm >> 6, b = gm & 63;
                    const int tidS = (b >> 4) * 64 + ((b >> 2) & 3) * 16 + lmu;
                    size_t idx = ((((size_t)t * 32 + ub) * 4 + (b & 3)) * 256 + tidS) * 4 + g;
                    P[idx] = acc[i][j][r] + bb;
                }
            } else {
#pragma unroll
                for (int r = 0; r < 4; r++)
                    C[(size_t)(gm0 + r) * N + gn] = acc[i][j][r] + bb;
            }
        }
    }
}

// ---------------------------------------------------------------------------
// Pack Whh (2,4H,H) fp32 -> bf16 B-fragments:
// Wpk[dir][ub(32)][g(4)][it(16)][lane(64)][8]
//   = Whh[dir][g*512 + ub*16 + (lane&15)][it*32 + (lane>>4)*8 + e]
// ---------------------------------------------------------------------------
__global__ __launch_bounds__(256) void pack_whh(
    const float* __restrict__ W, short* __restrict__ Wpk)
{
    int i = blockIdx.x * 256 + threadIdx.x;
    if (i >= 2 * G4_ * H_) return;
    int e = i & 7, lane = (i >> 3) & 63, it = (i >> 9) & 15;
    int g = (i >> 13) & 3, ub = (i >> 15) & 31, dir = (i >> 20) & 1;
    int lm = lane & 15, qq = lane >> 4;
    float v = W[((size_t)dir * G4_ + g * H_ + ub * 16 + lm) * H_
                + it * 32 + qq * 8 + e];
    Wpk[i] = f2b(v);
}

// ---------------------------------------------------------------------------
__global__ __launch_bounds__(256) void init_phase(
    const float* __restrict__ h0s, short* __restrict__ Ht,
    unsigned* __restrict__ bar, int zero_bar)
{
    int i = blockIdx.x * 256 + threadIdx.x;
    if (i < 2 * B_ * H_) Ht[i] = f2b(h0s[i]);
    if (zero_bar && i < 64) bar[i] = 0;
}

__global__ __launch_bounds__(256) void ht_to_f32(
    const short* __restrict__ Ht0, float* __restrict__ out)
{
    int i = blockIdx.x * 256 + threadIdx.x;
    if (i < 2 * B_ * H_) out[i] = b2f(Ht0[i]);
}

// ---------------------------------------------------------------------------
// Persistent phase kernel. grid (32, 2): block = 16 units, 1 dir.
// Whh in 64KB LDS (B-frag order). h via L3 (sc-bypass relaxed atomics).
// Packed XW: 4x dwordx4 lane-contiguous per thread per step.
// Per-wave fire-and-forget arrive + 32-slot ballot poll barrier.
// ---------------------------------------------------------------------------
__global__ __launch_bounds__(256, 1) void lstm_phase(
    const float* __restrict__ XW,   // packed (2,T,32,4,256,4) fp32
    const short* __restrict__ Wpk,  // packed Whh bf16
    short* __restrict__ Ht,         // (2buf,2dir,64b,512u) bf16
    const float* __restrict__ c0p,  // (2,B,H) fp32 initial c
    short* __restrict__ Y,          // (T,B,2H) bf16 or null
    unsigned* __restrict__ bar, int phase)
{
    __shared__ short Ws[32768];     // 64 KB packed weights
    __shared__ short Tb[64 * 24];   // transpose buffer (48B row stride)
    const int dir = blockIdx.y, ub = blockIdx.x, u0 = ub * 16;
    const int tid = threadIdx.x, w = tid >> 6, lane = tid & 63;
    const int lm = lane & 15, q = lane >> 4;

    const short* wsrc = Wpk + (size_t)(dir * 32 + ub) * 32768;
#pragma unroll
    for (int p = 0; p < 16; p++)
        gload16(wsrc + (tid + 256 * p) * 8, &Ws[(tid + 256 * p) * 8]);

    const int b0 = w * 16 + q * 4;   // this lane's 4 batch rows
    const int u = u0 + lm;           // this lane's hidden unit
    unsigned* slots = bar + dir * 32;

    float c[4];
    f32x4 xw[4];                     // [r] -> 4 gates
#pragma unroll
    for (int r = 0; r < 4; r++)
        c[r] = c0p[(size_t)dir * B_ * H_ + (size_t)(b0 + r) * H_ + u];
    {
        const int t0 = dir ? (T_ - 1) : 0;
        const float* xp = XW + ((size_t)dir * T_ + t0) * (B_ * G4_) + (size_t)ub * 4096;
#pragma unroll
        for (int r = 0; r < 4; r++)
            xw[r] = *(const f32x4*)(xp + r * 1024 + tid * 4);
    }
    __syncthreads();   // Ws resident

    for (int s = 0; s < T_; s++) {
        const int t = dir ? (T_ - 1 - s) : s;
        const short* Hc = Ht + ((size_t)((s & 1) * 2 + dir) << 15);

        // ---- h A-fragments (full h vector), L2-bypassing loads
        u64 hq[32];
#pragma unroll
        for (int it = 0; it < 16; it++) {
            const u64* hp = (const u64*)(Hc + (w * 16 + lm) * 512 + it * 32 + q * 8);
            hq[2 * it]     = __hip_atomic_load((u64*)hp,     __ATOMIC_RELAXED, __HIP_MEMORY_SCOPE_AGENT);
            hq[2 * it + 1] = __hip_atomic_load((u64*)hp + 1, __ATOMIC_RELAXED, __HIP_MEMORY_SCOPE_AGENT);
        }

        f32x4 acc[4];
#pragma unroll
        for (int g = 0; g < 4; g++)
#pragma unroll
            for (int r = 0; r < 4; r++) acc[g][r] = 0.f;

#pragma unroll
        for (int it = 0; it < 16; it++) {
            union { u64 q2[2]; bf16x8 v; } ua;
            ua.q2[0] = hq[2 * it]; ua.q2[1] = hq[2 * it + 1];
#pragma unroll
            for (int g = 0; g < 4; g++) {
                bf16x8 bv = *(const bf16x8*)&Ws[((g * 16 + it) * 64 + lane) * 8];
                acc[g] = __builtin_amdgcn_mfma_f32_16x16x32_bf16(ua.v, bv, acc[g], 0, 0, 0);
            }
        }

        // ---- pointwise gates; h -> LDS transpose tile
#pragma unroll
        for (int r = 0; r < 4; r++) {
            float gi = acc[0][r] + xw[r][0];
            float gf = acc[1][r] + xw[r][1];
            float gg = acc[2][r] + xw[r][2];
            float go = acc[3][r] + xw[r][3];
            float cc = fsig(gf) * c[r] + fsig(gi) * ftanh(gg);
            c[r] = cc;
            Tb[(b0 + r) * 24 + lm] = f2b(fsig(go) * ftanh(cc));
        }
        __syncthreads();

        // ---- h publish (u64 per thread) then Y
        {
            const int b = tid >> 2, qd = tid & 3;
            u64 v0 = *(const u64*)&Tb[b * 24 + qd * 4];
            short* Hn = Ht + ((size_t)(((s + 1) & 1) * 2 + dir) << 15);
            __hip_atomic_store((u64*)(Hn + b * 512 + u0 + qd * 4), v0,
                               __ATOMIC_RELAXED, __HIP_MEMORY_SCOPE_AGENT);
            if (Y)
                *(u64*)(Y + ((size_t)t * B_ + b) * (2 * H_) + dir * H_ + u0 + qd * 4) = v0;
        }
        __asm__ volatile("s_waitcnt vmcnt(0)" ::: "memory");

        const unsigned tgt4 = (unsigned)(phase * T_ + s + 1) * 4u;
        if (lane == 0)
            __hip_atomic_fetch_add(&slots[ub], 1u, __ATOMIC_RELAXED, __HIP_MEMORY_SCOPE_AGENT);

        // prefetch next step's packed XW during the spin
        if (s < T_ - 1) {
            const int tn = dir ? (T_ - 2 - s) : (s + 1);
            const float* xp = XW + ((size_t)dir * T_ + tn) * (B_ * G4_) + (size_t)ub * 4096;
#pragma unroll
            for (int r = 0; r < 4; r++)
                xw[r] = *(const f32x4*)(xp + r * 1024 + tid * 4);
        }

        unsigned v;
        do {
            __builtin_amdgcn_s_sleep(1);
            v = (lane < 32)
                ? __hip_atomic_load(&slots[lane], __ATOMIC_RELAXED, __HIP_MEMORY_SCOPE_AGENT)
                : tgt4;
        } while (__any(v < tgt4));
        __syncthreads();
    }
}

// ---------------------------------------------------------------------------
// fp32 GEMM for tiny attention matmuls (bounds-checked), act 0/1/2
// ---------------------------------------------------------------------------
__global__ __launch_bounds__(256) void gemm_bt(
    const float* __restrict__ A, const float* __restrict__ Bm,
    float* __restrict__ C, int M, int N, int K,
    const float* __restrict__ bias1, int act)
{
    __shared__ float As[16][68];
    __shared__ float Bs[16][68];
    const int tid = threadIdx.x;
    const int m_base = blockIdx.y * 64;
    const int n_base = blockIdx.x * 64;
    const int tm = tid >> 4, tn = tid & 15;
    float acc[4][4] = {};

    for (int k0 = 0; k0 < K; k0 += 16) {
#pragma unroll
        for (int i = 0; i < 4; i++) {
            int idx = tid * 4 + i;
            int r = idx >> 4, kk = idx & 15;
            int gm = m_base + r, gk = k0 + kk;
            As[kk][r] = (gm < M && gk < K) ? A[(size_t)gm * K + gk] : 0.f;
            int gn = n_base + r;
            Bs[kk][r] = (gn < N && gk < K) ? Bm[(size_t)gn * K + gk] : 0.f;
        }
        __syncthreads();
#pragma unroll
        for (int kk = 0; kk < 16; kk++) {
            float4 av = *(const float4*)&As[kk][tm * 4];
            float4 bv = *(const float4*)&Bs[kk][tn * 4];
            float a[4] = {av.x, av.y, av.z, av.w};
            float b[4] = {bv.x, bv.y, bv.z, bv.w};
#pragma unroll
            for (int i = 0; i < 4; i++)
#pragma unroll
                for (int j = 0; j < 4; j++)
                    acc[i][j] = fmaf(a[i], b[j], acc[i][j]);
        }
        __syncthreads();
    }
#pragma unroll
    for (int i = 0; i < 4; i++) {
        int gm = m_base + tm * 4 + i;
        if (gm >= M) continue;
#pragma unroll
        for (int j = 0; j < 4; j++) {
            int gn = n_base + tn * 4 + j;
            if (gn >= N) continue;
            float v = acc[i][j];
            if (bias1) v += bias1[gn];
            if (act == 1) v = tanhf(v);
            else if (act == 2) v = expf(v);
            C[(size_t)gm * N + gn] = v;
        }
    }
}

// ---------------------------------------------------------------------------
__global__ __launch_bounds__(256) void conv_f2b(
    const float* __restrict__ src, short* __restrict__ dst, int n)
{
    int i = blockIdx.x * 256 + threadIdx.x;
    if (i < n) dst[i] = f2b(src[i]);
}
__global__ __launch_bounds__(256) void conv_f2b_pad(
    const float* __restrict__ src, short* __restrict__ dst,
    int rows, int kin, int kp)
{
    int i = blockIdx.x * 256 + threadIdx.x;
    if (i < rows * kp) {
        int r = i / kp, k = i % kp;
        dst[i] = (k < kin) ? f2b(src[(size_t)r * kin + k]) : (short)0;
    }
}

__global__ __launch_bounds__(256) void attn_alpha(
    const float* __restrict__ E, float* __restrict__ AB)
{
    const int b = blockIdx.x, tid = threadIdx.x;
    __shared__ float red[256];
    __shared__ float adj[152];
    float v = 0.f;
    if (tid < 150) {
        int d = tid / F_, j = tid % F_;
        v = E[((size_t)d * B_ + b) * F_ + j];
    }
    red[tid] = v; __syncthreads();
    for (int s2 = 128; s2 > 0; s2 >>= 1) {
        if (tid < s2) red[tid] += red[tid + s2];
        __syncthreads();
    }
    float total = red[0]; __syncthreads();
    float alpha = v / total;
    float m = (tid < 150 && alpha >= 0.1f) ? 1.f : 0.f;
    red[tid] = m; __syncthreads();
    for (int s2 = 128; s2 > 0; s2 >>= 1) {
        if (tid < s2) red[tid] += red[tid + s2];
        __syncthreads();
    }
    float cnt = red[0]; __syncthreads();
    red[tid] = m * alpha; __syncthreads();
    for (int s2 = 128; s2 > 0; s2 >>= 1) {
        if (tid < s2) red[tid] += red[tid + s2];
        __syncthreads();
    }
    float selsum = red[0]; __syncthreads();
    float selmean = selsum / fmaxf(cnt, 1.f);
    if (tid < 150) adj[tid] = (m > 0.f) ? selmean : alpha;
    __syncthreads();
    if (tid < F_) AB[(size_t)b * F_ + tid] = 0.5f * (adj[tid] + adj[F_ + tid]);
}

__global__ __launch_bounds__(256) void scale_xb(
    const float* __restrict__ x, const float* __restrict__ AB,
    short* __restrict__ xb)
{
    int i = blockIdx.x * 256 + threadIdx.x;
    if (i < TB_ * KP_) {
        int r = i >> 7, k = i & 127;
        if (k < F_) {
            int b = r % B_;
            xb[i] = f2b(x[(size_t)r * F_ + k] * AB[(size_t)b * F_ + k]);
        } else xb[i] = 0;
    }
}

// ---------------------------------------------------------------------------
extern "C" void kernel_launch(void* const* d_in, const int* in_sizes, int n_in,
                              void* d_out, int out_size, void* d_ws, size_t ws_size,
                              hipStream_t stream)
{
    (void)in_sizes; (void)n_in; (void)out_size; (void)ws_size;
    const float* x       = (const float*)d_in[0];
    const float* h0      = (const float*)d_in[1];
    const float* c0      = (const float*)d_in[2];
    const float* sa_Wih  = (const float*)d_in[3];
    const float* sa_Whh  = (const float*)d_in[4];
    const float* sa_bih  = (const float*)d_in[5];
    const float* sa_bhh  = (const float*)d_in[6];
    const float* m0_Wih  = (const float*)d_in[7];
    const float* m0_Whh  = (const float*)d_in[8];
    const float* m0_bih  = (const float*)d_in[9];
    const float* m0_bhh  = (const float*)d_in[10];
    const float* mL_Wih  = (const float*)d_in[11];
    const float* mL_Whh  = (const float*)d_in[12];
    const float* mL_bih  = (const float*)d_in[13];
    const float* mL_bhh  = (const float*)d_in[14];
    const float* safc1_W = (const float*)d_in[15];
    const float* safc1_b = (const float*)d_in[16];
    const float* safc2_W = (const float*)d_in[17];
    const float* safc2_b = (const float*)d_in[18];
    const float* fc1_W   = (const float*)d_in[19];
    const float* fc1_b   = (const float*)d_in[20];

    char* cur = (char*)d_ws;
    auto alloc = [&](size_t bytes) {
        char* p = cur; cur += (bytes + 255) & ~(size_t)255; return p;
    };
    float*    XW   = (float*)alloc((size_t)2 * TB_ * G4_ * 4);   // packed
    float*    T1b  = (float*)alloc(2 * B_ * H_ * 4);
    float*    Eb   = (float*)alloc(2 * B_ * F_ * 4);
    float*    AB   = (float*)alloc(B_ * F_ * 4);
    float*    saHf = (float*)alloc(2 * B_ * H_ * 4);
    short*    xb   = (short*)alloc((size_t)TB_ * KP_ * 2);
    short*    Y0b  = (short*)alloc((size_t)TB_ * 2 * H_ * 2);
    short*    Y1b  = (short*)alloc((size_t)TB_ * 2 * H_ * 2);
    short*    Ht   = (short*)alloc((size_t)2 * 2 * B_ * H_ * 2);
    short*    Wpk  = (short*)alloc((size_t)2 * G4_ * H_ * 2);
    short*    Wihb = (short*)alloc((size_t)2 * G4_ * KP_ * 2);
    short*    WihbL= (short*)alloc((size_t)2 * G4_ * 2 * H_ * 2);
    short*    fc1b = (short*)alloc((size_t)H_ * 2 * H_ * 2);
    unsigned* bar  = (unsigned*)alloc(256);

    auto cv = [&](const float* s, short* d, int n) {
        conv_f2b<<<(n + 255) / 256, 256, 0, stream>>>(s, d, n);
    };
    auto g16 = [&](const short* Ap, const short* Bp, float* Cp, float* Pp,
                   int M, int N, int K, const float* b1, const float* b2) {
        gemm_bf16<<<dim3(N / 128, M / 128), 256, 0, stream>>>(Ap, Bp, Cp, Pp, M, N, K, b1, b2);
    };
    auto phase = [&](const float* Whh_p, const float* h0p, const float* c0p,
                     short* Yout, int pidx) {
        pack_whh<<<(2 * G4_ * H_ + 255) / 256, 256, 0, stream>>>(Whh_p, Wpk);
        init_phase<<<256, 256, 0, stream>>>(h0p, Ht, bar, pidx == 0 ? 1 : 0);
        lstm_phase<<<dim3(32, 2), 256, 0, stream>>>(XW, Wpk, Ht, c0p, Yout, bar, pidx);
    };

    cv(fc1_W, fc1b, H_ * 2 * H_);

    // ---- Phase A: SA BiLSTM ----
    conv_f2b_pad<<<(TB_ * KP_ + 255) / 256, 256, 0, stream>>>(x, xb, TB_, F_, KP_);
    conv_f2b_pad<<<(2 * G4_ * KP_ + 255) / 256, 256, 0, stream>>>(sa_Wih, Wihb, 2 * G4_, F_, KP_);
    for (int d = 0; d < 2; d++)
        g16(xb, Wihb + (size_t)d * G4_ * KP_, nullptr, XW + (size_t)d * TB_ * G4_,
            TB_, G4_, KP_, sa_bih + d * G4_, sa_bhh + d * G4_);
    phase(sa_Whh, h0, c0, nullptr, 0);
    ht_to_f32<<<256, 256, 0, stream>>>(Ht, saHf);   // final h in buffer 0
    gemm_bt<<<dim3(8, 2), 256, 0, stream>>>(saHf, safc1_W, T1b, 2 * B_, H_, H_, safc1_b, 1);
    gemm_bt<<<dim3(2, 2), 256, 0, stream>>>(T1b, safc2_W, Eb, 2 * B_, F_, H_, safc2_b, 2);
    attn_alpha<<<B_, 256, 0, stream>>>(Eb, AB);
    scale_xb<<<(TB_ * KP_ + 255) / 256, 256, 0, stream>>>(x, AB, xb);

    // ---- Phase B: main layer 0 ----
    conv_f2b_pad<<<(2 * G4_ * KP_ + 255) / 256, 256, 0, stream>>>(m0_Wih, Wihb, 2 * G4_, F_, KP_);
    for (int d = 0; d < 2; d++)
        g16(xb, Wihb + (size_t)d * G4_ * KP_, nullptr, XW + (size_t)d * TB_ * G4_,
            TB_, G4_, KP_, m0_bih + d * G4_, m0_bhh + d * G4_);
    phase(m0_Whh, h0, c0, Y0b, 1);

    // ---- Phase C: main layer 1 ----
    cv(mL_Wih, WihbL, 2 * G4_ * 2 * H_);
    for (int d = 0; d < 2; d++)
        g16(Y0b, WihbL + (size_t)d * G4_ * 2 * H_, nullptr, XW + (size_t)d * TB_ * G4_,
            TB_, G4_, 2 * H_, mL_bih + d * G4_, mL_bhh + d * G4_);
    phase(mL_Whh, h0 + 2 * B_ * H_, c0 + 2 * B_ * H_, Y1b, 2);

    // ---- Phase D: main layer 2 ----
    cv(mL_Wih + (size_t)2 * G4_ * 2 * H_, WihbL, 2 * G4_ * 2 * H_);
    for (int d = 0; d < 2; d++)
        g16(Y1b, WihbL + (size_t)d * G4_ * 2 * H_, nullptr, XW + (size_t)d * TB_ * G4_,
            TB_, G4_, 2 * H_, mL_bih + (2 + d) * G4_, mL_bhh + (2 + d) * G4_);
    phase(mL_Whh + (size_t)2 * G4_ * H_, h0 + 4 * B_ * H_, c0 + 4 * B_ * H_, Y0b, 3);

    // ---- FC1 ----
    g16(Y0b, fc1b, (float*)d_out, nullptr, TB_, H_, 2 * H_, fc1_b, nullptr);
}